// Round 3
// baseline (5327.165 us; speedup 1.0000x reference)
//
#include <hip/hip_runtime.h>
#include <cstdint>

constexpr int Bc = 2, Sc = 2048, Hc = 1024, NHc = 16, HDc = 64, PFc = 4096, Lc = 6;
constexpr float EPSc = 1e-5f;

using f32x4  = __attribute__((ext_vector_type(4))) float;
using bf16x8 = __attribute__((ext_vector_type(8))) __bf16;
using bf16x4 = __attribute__((ext_vector_type(4))) __bf16;

__device__ __forceinline__ f32x4 mfma16(bf16x8 a, bf16x8 b, f32x4 c) {
    return __builtin_amdgcn_mfma_f32_16x16x32_bf16(a, b, c, 0, 0, 0);
}

// async global->LDS, 16B/lane; LDS dest wave-uniform base (+lane*16 by HW)
__device__ __forceinline__ void gload_lds16(const void* g, void* l) {
    __builtin_amdgcn_global_load_lds(
        (__attribute__((address_space(1))) void*)(uintptr_t)g,
        (__attribute__((address_space(3))) void*)(uint32_t)(uintptr_t)l,
        16, 0, 0);
}

struct HL { __bf16 h, l; };
__device__ __forceinline__ HL split2(float v) {
    HL r;
    r.h = (__bf16)v;              // hi: bf16 round
    r.l = (__bf16)(v - (float)r.h); // lo: residual rounded to bf16
    return r;
}

// ---------------------------------------------------------------------------
// Embed: src = in * sqrt(H) + pos ; writes f32 master + split bf16 (hi,lo)
// ---------------------------------------------------------------------------
__global__ __launch_bounds__(256) void embed_kernel(
    const float* __restrict__ in, const float* __restrict__ pos,
    float* __restrict__ sf, __bf16* __restrict__ sh, __bf16* __restrict__ sl)
{
    const int n4 = (Bc * Sc * Hc) / 4;
    const int pmask = (Sc * Hc / 4) - 1;
    for (int i = blockIdx.x * 256 + threadIdx.x; i < n4; i += gridDim.x * 256) {
        float4 a = ((const float4*)in)[i];
        float4 p = ((const float4*)pos)[i & pmask];
        float4 r;
        r.x = a.x * 32.f + p.x; r.y = a.y * 32.f + p.y;
        r.z = a.z * 32.f + p.z; r.w = a.w * 32.f + p.w;
        ((float4*)sf)[i] = r;
        HL e0 = split2(r.x), e1 = split2(r.y), e2 = split2(r.z), e3 = split2(r.w);
        bf16x4 hh = { e0.h, e1.h, e2.h, e3.h };
        bf16x4 ll = { e0.l, e1.l, e2.l, e3.l };
        ((bf16x4*)sh)[i] = hh;
        ((bf16x4*)sl)[i] = ll;
    }
}

// ---------------------------------------------------------------------------
// Split-precision GEMM: C = act(A @ W + bias), A = Ahi(+Alo) bf16, W f32.
// acc += Ahi*Whi (+ Alo*Whi if ASPLIT) + Ahi*Wlo   (Wlo = W - bf16(W))
// 128x128 tile, BK=64, 4 waves. A via global_load_lds w/ pre-swizzled source;
// W reg-staged f32 -> (hi,lo) bf16, transposed [n][k] in LDS, same swizzle.
// OUTMODE: 0 = f32, 1 = bf16, 2 = split (hi,lo)
// ---------------------------------------------------------------------------
template<int ASPLIT, int OUTMODE, bool RELU>
__global__ __launch_bounds__(256) void gemm_kernel(
    const __bf16* __restrict__ Ahi, const __bf16* __restrict__ Alo,
    const float* __restrict__ Bw, const float* __restrict__ bias,
    void* __restrict__ out0, void* __restrict__ out1,
    int M, int N, int K)
{
    __shared__ alignas(16) __bf16 AldsH[128 * 64];
    __shared__ alignas(16) __bf16 AldsL[ASPLIT ? 128 * 64 : 8];
    __shared__ alignas(16) __bf16 BldsH[128 * 64];
    __shared__ alignas(16) __bf16 BldsL[128 * 64];

    const int tid  = threadIdx.x;
    const int lane = tid & 63;
    const int wave = tid >> 6;
    const int lr   = lane & 15;
    const int lg   = lane >> 4;
    const int m0   = blockIdx.y * 128;
    const int n0   = blockIdx.x * 128;
    const int wm   = (wave >> 1) * 64;
    const int wn   = (wave & 1) * 64;
    const int bn   = tid & 127;          // B-staging column within tile
    const int bkh  = (tid >> 7) * 32;    // B-staging k half

    f32x4 acc[4][4] = {};

    const float* bsrc0 = Bw + (size_t)bkh * N + n0 + bn;

    for (int k0 = 0; k0 < K; k0 += 64) {
        // ---- A tiles via global_load_lds (source pre-swizzled, dest linear) ----
        #pragma unroll
        for (int c = 0; c < 4; ++c) {
            int li  = c * 256 + tid;
            int row = li >> 3;
            int pcb = (li & 7) << 4;
            int lcb = pcb ^ ((row & 7) << 4);
            size_t goff = (size_t)(m0 + row) * K + k0 + (lcb >> 1);
            size_t loff = (size_t)(c * 256 + wave * 64) * 16;  // wave-uniform
            gload_lds16(Ahi + goff, (char*)AldsH + loff);
            if constexpr (ASPLIT)
                gload_lds16(Alo + goff, (char*)AldsL + loff);
        }
        // ---- W tile: f32 loads, split to (hi,lo), transposed + swizzled ----
        const float* bs = bsrc0 + (size_t)k0 * N;
        #pragma unroll
        for (int c = 0; c < 4; ++c) {
            bf16x8 ph, pl;
            #pragma unroll
            for (int j = 0; j < 8; ++j) {
                HL e = split2(bs[(size_t)(c * 8 + j) * N]);
                ph[j] = e.h;
                pl[j] = e.l;
            }
            int lcb = bkh * 2 + c * 16;
            int pcb = lcb ^ ((bn & 7) << 4);
            *(bf16x8*)((char*)BldsH + bn * 128 + pcb) = ph;
            *(bf16x8*)((char*)BldsL + bn * 128 + pcb) = pl;
        }
        __syncthreads();

        // ---- fragments ----
        bf16x8 ah[2][4], al[2][4], bh[2][4], bl[2][4];
        #pragma unroll
        for (int ks = 0; ks < 2; ++ks) {
            #pragma unroll
            for (int i = 0; i < 4; ++i) {
                int ra = wm + i * 16 + lr;
                int pa = (ks * 64 + lg * 16) ^ ((ra & 7) << 4);
                ah[ks][i] = *(const bf16x8*)((const char*)AldsH + ra * 128 + pa);
                if constexpr (ASPLIT)
                    al[ks][i] = *(const bf16x8*)((const char*)AldsL + ra * 128 + pa);
                int rb = wn + i * 16 + lr;
                int pb = (ks * 64 + lg * 16) ^ ((rb & 7) << 4);
                bh[ks][i] = *(const bf16x8*)((const char*)BldsH + rb * 128 + pb);
                bl[ks][i] = *(const bf16x8*)((const char*)BldsL + rb * 128 + pb);
            }
        }
        #pragma unroll
        for (int ks = 0; ks < 2; ++ks)
            #pragma unroll
            for (int mi = 0; mi < 4; ++mi)
                #pragma unroll
                for (int ni = 0; ni < 4; ++ni) {
                    acc[mi][ni] = mfma16(ah[ks][mi], bh[ks][ni], acc[mi][ni]);
                    if constexpr (ASPLIT)
                        acc[mi][ni] = mfma16(al[ks][mi], bh[ks][ni], acc[mi][ni]);
                    acc[mi][ni] = mfma16(ah[ks][mi], bl[ks][ni], acc[mi][ni]);
                }
        __syncthreads();
    }

    // ---- epilogue ----
    #pragma unroll
    for (int ni = 0; ni < 4; ++ni) {
        int col = n0 + wn + ni * 16 + lr;
        float bv = bias[col];
        #pragma unroll
        for (int mi = 0; mi < 4; ++mi) {
            int rowb = m0 + wm + mi * 16 + lg * 4;
            #pragma unroll
            for (int r = 0; r < 4; ++r) {
                float v = acc[mi][ni][r] + bv;
                if (RELU) v = fmaxf(v, 0.f);
                size_t idx = (size_t)(rowb + r) * N + col;
                if constexpr (OUTMODE == 0) {
                    ((float*)out0)[idx] = v;
                } else if constexpr (OUTMODE == 1) {
                    ((__bf16*)out0)[idx] = (__bf16)v;
                } else {
                    HL e = split2(v);
                    ((__bf16*)out0)[idx] = e.h;
                    ((__bf16*)out1)[idx] = e.l;
                }
            }
        }
    }
}

// ---------------------------------------------------------------------------
// Flash attention with split-precision QK^T (q,k as hi+lo bf16).
// Block = 4 waves; wave owns 16 q-rows; 64 keys/iter. Swapped QK^T.
// ctx written split (hi,lo) for the following Wo GEMM.
// ---------------------------------------------------------------------------
__global__ __launch_bounds__(256) void attn_kernel(
    const __bf16* __restrict__ Qh, const __bf16* __restrict__ Ql,
    const __bf16* __restrict__ Kh, const __bf16* __restrict__ Kl,
    const __bf16* __restrict__ V,
    __bf16* __restrict__ Oh, __bf16* __restrict__ Ol)
{
    __shared__ alignas(16) char plds[4][2048];
    const int lane = threadIdx.x & 63, wave = threadIdx.x >> 6;
    const int lr = lane & 15, lg = lane >> 4;
    const int h = blockIdx.y, b = blockIdx.z;
    const int q0 = blockIdx.x * 64 + wave * 16;
    char* pl = plds[wave];

    const size_t qrow = ((size_t)b * Sc + q0 + lr) * Hc + h * HDc;
    bf16x8 qh0 = *(const bf16x8*)(Qh + qrow + lg * 8);
    bf16x8 qh1 = *(const bf16x8*)(Qh + qrow + 32 + lg * 8);
    bf16x8 ql0 = *(const bf16x8*)(Ql + qrow + lg * 8);
    bf16x8 ql1 = *(const bf16x8*)(Ql + qrow + 32 + lg * 8);

    f32x4 o[4] = {};
    float m = -1e30f, lsum = 0.f;

    for (int kt = 0; kt < Sc / 64; ++kt) {
        const size_t krow = ((size_t)b * Sc + kt * 64 + lr) * Hc + h * HDc + lg * 8;
        f32x4 s[4];
        #pragma unroll
        for (int kg = 0; kg < 4; ++kg) {
            size_t off = krow + (size_t)kg * 16 * Hc;
            bf16x8 kh0 = *(const bf16x8*)(Kh + off);
            bf16x8 kh1 = *(const bf16x8*)(Kh + off + 32);
            bf16x8 kl0 = *(const bf16x8*)(Kl + off);
            bf16x8 kl1 = *(const bf16x8*)(Kl + off + 32);
            f32x4 t = {};
            t = mfma16(kh0, qh0, t);  t = mfma16(kh1, qh1, t);   // hi*hi
            t = mfma16(kl0, qh0, t);  t = mfma16(kl1, qh1, t);   // lo*hi
            t = mfma16(kh0, ql0, t);  t = mfma16(kh1, ql1, t);   // hi*lo
            s[kg] = t;
        }
        float mt = -1e30f;
        #pragma unroll
        for (int kg = 0; kg < 4; ++kg)
            #pragma unroll
            for (int r = 0; r < 4; ++r) {
                s[kg][r] *= 0.125f;
                mt = fmaxf(mt, s[kg][r]);
            }
        mt = fmaxf(mt, __shfl_xor(mt, 16));
        mt = fmaxf(mt, __shfl_xor(mt, 32));
        float mnew = fmaxf(m, mt);
        float fac = __expf(m - mnew);
        m = mnew;
        float ps = 0.f;
        #pragma unroll
        for (int kg = 0; kg < 4; ++kg)
            #pragma unroll
            for (int r = 0; r < 4; ++r) {
                float p = __expf(s[kg][r] - mnew);
                ps += p;
                s[kg][r] = p;
            }
        ps += __shfl_xor(ps, 16);
        ps += __shfl_xor(ps, 32);
        lsum = lsum * fac + ps;
        #pragma unroll
        for (int r = 0; r < 4; ++r) {
            float fr = __shfl(fac, (lg << 4) | (lg * 4 + r));
            #pragma unroll
            for (int nd = 0; nd < 4; ++nd) o[nd][r] *= fr;
        }
        // P -> LDS (bf16), [key][q] with bank swizzle
        #pragma unroll
        for (int kg = 0; kg < 4; ++kg)
            #pragma unroll
            for (int r = 0; r < 4; ++r) {
                int key = kg * 16 + lg * 4 + r;
                int pa  = key * 32 + ((lr * 2) ^ (((key >> 2) & 3) << 3));
                *(__bf16*)(pl + pa) = (__bf16)s[kg][r];
            }
        // PV
        const __bf16* vp = V + ((size_t)b * Sc + kt * 64) * Hc + h * HDc;
        #pragma unroll
        for (int kh2 = 0; kh2 < 2; ++kh2) {
            bf16x8 paf;
            #pragma unroll
            for (int j = 0; j < 8; ++j) {
                int key = kh2 * 32 + lg * 8 + j;
                int pa  = key * 32 + ((lr * 2) ^ (((key >> 2) & 3) << 3));
                paf[j] = *(const __bf16*)(pl + pa);
            }
            #pragma unroll
            for (int nd = 0; nd < 4; ++nd) {
                bf16x8 vbf;
                #pragma unroll
                for (int j = 0; j < 8; ++j)
                    vbf[j] = vp[(size_t)(kh2 * 32 + lg * 8 + j) * Hc + nd * 16 + lr];
                o[nd] = mfma16(paf, vbf, o[nd]);
            }
        }
    }
    #pragma unroll
    for (int r = 0; r < 4; ++r) {
        float lv  = __shfl(lsum, (lg << 4) | (lg * 4 + r));
        float inv = 1.f / lv;
        size_t orow = ((size_t)b * Sc + q0 + lg * 4 + r) * Hc + h * HDc;
        #pragma unroll
        for (int nd = 0; nd < 4; ++nd) {
            HL e = split2(o[nd][r] * inv);
            Oh[orow + nd * 16 + lr] = e.h;
            Ol[orow + nd * 16 + lr] = e.l;
        }
    }
}

// ---------------------------------------------------------------------------
// Fused residual + LayerNorm: out = LN(xr + y)*g + b ; f32 master + split bf16
// ---------------------------------------------------------------------------
__global__ __launch_bounds__(256) void ln_kernel(
    const float* __restrict__ xr, const float* __restrict__ y,
    const float* __restrict__ g, const float* __restrict__ beta,
    float* __restrict__ of, __bf16* __restrict__ oh, __bf16* __restrict__ ol)
{
    __shared__ float red[2][4];
    const int row = blockIdx.x, t = threadIdx.x;
    const int lane = t & 63, wave = t >> 6;
    const int idx = row * 256 + t;
    float4 a = ((const float4*)xr)[idx];
    float4 c = ((const float4*)y)[idx];
    float4 v;
    v.x = a.x + c.x; v.y = a.y + c.y; v.z = a.z + c.z; v.w = a.w + c.w;
    float s1 = v.x + v.y + v.z + v.w;
    float s2 = v.x * v.x + v.y * v.y + v.z * v.z + v.w * v.w;
    #pragma unroll
    for (int off = 1; off < 64; off <<= 1) {
        s1 += __shfl_xor(s1, off);
        s2 += __shfl_xor(s2, off);
    }
    if (lane == 0) { red[0][wave] = s1; red[1][wave] = s2; }
    __syncthreads();
    s1 = red[0][0] + red[0][1] + red[0][2] + red[0][3];
    s2 = red[1][0] + red[1][1] + red[1][2] + red[1][3];
    const float mu   = s1 * (1.f / Hc);
    const float var  = s2 * (1.f / Hc) - mu * mu;
    const float rstd = rsqrtf(var + EPSc);
    float4 gg = ((const float4*)g)[t];
    float4 bb = ((const float4*)beta)[t];
    float4 r;
    r.x = (v.x - mu) * rstd * gg.x + bb.x;
    r.y = (v.y - mu) * rstd * gg.y + bb.y;
    r.z = (v.z - mu) * rstd * gg.z + bb.z;
    r.w = (v.w - mu) * rstd * gg.w + bb.w;
    ((float4*)of)[idx] = r;
    HL e0 = split2(r.x), e1 = split2(r.y), e2 = split2(r.z), e3 = split2(r.w);
    bf16x4 hh = { e0.h, e1.h, e2.h, e3.h };
    bf16x4 ll = { e0.l, e1.l, e2.l, e3.l };
    ((bf16x4*)oh)[idx] = hh;
    ((bf16x4*)ol)[idx] = ll;
}

// ---------------------------------------------------------------------------
extern "C" void kernel_launch(void* const* d_in, const int* in_sizes, int n_in,
                              void* d_out, int out_size, void* d_ws, size_t ws_size,
                              hipStream_t stream)
{
    const float* inp = (const float*)d_in[0];
    const float* pos = (const float*)d_in[1];
    const float* Wq  = (const float*)d_in[2];
    const float* bq  = (const float*)d_in[3];
    const float* Wk  = (const float*)d_in[4];
    const float* bk  = (const float*)d_in[5];
    const float* Wv  = (const float*)d_in[6];
    const float* bv  = (const float*)d_in[7];
    const float* Wo  = (const float*)d_in[8];
    const float* bo  = (const float*)d_in[9];
    const float* lng = (const float*)d_in[10];
    const float* lnb = (const float*)d_in[11];
    const float* W1  = (const float*)d_in[12];
    const float* b1  = (const float*)d_in[13];
    const float* W2  = (const float*)d_in[14];
    const float* b2  = (const float*)d_in[15];

    char* ws = (char*)d_ws;
    const size_t MB = 1u << 20;
    float*  src_f = (float*)(ws);              // 16 MB
    __bf16* src_h = (__bf16*)(ws + 16 * MB);   //  8 MB
    __bf16* src_l = (__bf16*)(ws + 24 * MB);   //  8 MB
    __bf16* qh    = (__bf16*)(ws + 32 * MB);   //  8 MB
    __bf16* ql    = (__bf16*)(ws + 40 * MB);
    __bf16* kh    = (__bf16*)(ws + 48 * MB);
    __bf16* kl    = (__bf16*)(ws + 56 * MB);
    __bf16* vv    = (__bf16*)(ws + 64 * MB);
    __bf16* ch    = (__bf16*)(ws + 72 * MB);
    __bf16* cl    = (__bf16*)(ws + 80 * MB);
    __bf16* h1    = (__bf16*)(ws + 32 * MB);   // 32 MB alias over qh..kl (dead by FFN)
    float*  tmp   = (float*)(ws + 88 * MB);    // 16 MB ; total 104 MB

    const int M = Bc * Sc;  // 4096

    embed_kernel<<<2048, 256, 0, stream>>>(inp, pos, src_f, src_h, src_l);

    for (int l = 0; l < Lc; ++l) {
        const size_t wHH = (size_t)l * Hc * Hc;
        const size_t wH  = (size_t)l * Hc;
        gemm_kernel<1, 2, false><<<dim3(Hc / 128, M / 128), 256, 0, stream>>>(
            src_h, src_l, Wq + wHH, bq + wH, qh, ql, M, Hc, Hc);
        gemm_kernel<1, 2, false><<<dim3(Hc / 128, M / 128), 256, 0, stream>>>(
            src_h, src_l, Wk + wHH, bk + wH, kh, kl, M, Hc, Hc);
        gemm_kernel<1, 1, false><<<dim3(Hc / 128, M / 128), 256, 0, stream>>>(
            src_h, src_l, Wv + wHH, bv + wH, vv, nullptr, M, Hc, Hc);
        attn_kernel<<<dim3(Sc / 64, NHc, Bc), 256, 0, stream>>>(qh, ql, kh, kl, vv, ch, cl);
        gemm_kernel<1, 0, false><<<dim3(Hc / 128, M / 128), 256, 0, stream>>>(
            ch, cl, Wo + wHH, bo + wH, tmp, nullptr, M, Hc, Hc);
        ln_kernel<<<M, 256, 0, stream>>>(src_f, tmp, lng + wH, lnb + wH, src_f, src_h, src_l);
        gemm_kernel<1, 1, true><<<dim3(PFc / 128, M / 128), 256, 0, stream>>>(
            src_h, src_l, W1 + (size_t)l * Hc * PFc, b1 + (size_t)l * PFc, h1, nullptr, M, PFc, Hc);
        gemm_kernel<0, 0, false><<<dim3(Hc / 128, M / 128), 256, 0, stream>>>(
            h1, nullptr, W2 + (size_t)l * PFc * Hc, b2 + wH, tmp, nullptr, M, Hc, PFc);
        float* dst = (l == Lc - 1) ? (float*)d_out : src_f;
        ln_kernel<<<M, 256, 0, stream>>>(src_f, tmp, lng + wH, lnb + wH, dst, src_h, src_l);
    }
}

// Round 4
// 2691.632 us; speedup vs baseline: 1.9792x; 1.9792x over previous
//
#include <hip/hip_runtime.h>
#include <cstdint>

constexpr int Bc = 2, Sc = 2048, Hc = 1024, NHc = 16, HDc = 64, PFc = 4096, Lc = 6;
constexpr float EPSc = 1e-5f;

using f32x4  = __attribute__((ext_vector_type(4))) float;
using bf16x8 = __attribute__((ext_vector_type(8))) __bf16;
using bf16x4 = __attribute__((ext_vector_type(4))) __bf16;

__device__ __forceinline__ f32x4 mfma16(bf16x8 a, bf16x8 b, f32x4 c) {
    return __builtin_amdgcn_mfma_f32_16x16x32_bf16(a, b, c, 0, 0, 0);
}

__device__ __forceinline__ void gload_lds16(const void* g, void* l) {
    __builtin_amdgcn_global_load_lds(
        (__attribute__((address_space(1))) void*)(uintptr_t)g,
        (__attribute__((address_space(3))) void*)(uint32_t)(uintptr_t)l,
        16, 0, 0);
}

struct HL { __bf16 h, l; };
__device__ __forceinline__ HL split2(float v) {
    HL r;
    r.h = (__bf16)v;
    r.l = (__bf16)(v - (float)r.h);
    return r;
}

// ---------------------------------------------------------------------------
// Embed: src = in*32 + pos ; f32 master + split bf16 (layer-0 QKV needs split A)
// ---------------------------------------------------------------------------
__global__ __launch_bounds__(256) void embed_kernel(
    const float* __restrict__ in, const float* __restrict__ pos,
    float* __restrict__ sf, __bf16* __restrict__ sh, __bf16* __restrict__ sl)
{
    const int n4 = (Bc * Sc * Hc) / 4;
    const int pmask = (Sc * Hc / 4) - 1;
    for (int i = blockIdx.x * 256 + threadIdx.x; i < n4; i += gridDim.x * 256) {
        float4 a = ((const float4*)in)[i];
        float4 p = ((const float4*)pos)[i & pmask];
        float4 r;
        r.x = a.x * 32.f + p.x; r.y = a.y * 32.f + p.y;
        r.z = a.z * 32.f + p.z; r.w = a.w * 32.f + p.w;
        ((float4*)sf)[i] = r;
        HL e0 = split2(r.x), e1 = split2(r.y), e2 = split2(r.z), e3 = split2(r.w);
        bf16x4 hh = { e0.h, e1.h, e2.h, e3.h };
        bf16x4 ll = { e0.l, e1.l, e2.l, e3.l };
        ((bf16x4*)sh)[i] = hh;
        ((bf16x4*)sl)[i] = ll;
    }
}

// ---------------------------------------------------------------------------
// Generic GEMM: C = act(A @ W + bias). A bf16 (hi[,lo]), W f32 split to hi+lo.
// 128x128 tile, BK=64, 4 waves. OUTMODE: 0=f32, 1=bf16.
// ---------------------------------------------------------------------------
template<int ASPLIT, int OUTMODE, bool RELU>
__global__ __launch_bounds__(256) void gemm_kernel(
    const __bf16* __restrict__ Ahi, const __bf16* __restrict__ Alo,
    const float* __restrict__ Bw, const float* __restrict__ bias,
    void* __restrict__ out, int M, int N, int K)
{
    __shared__ alignas(16) __bf16 AldsH[128 * 64];
    __shared__ alignas(16) __bf16 AldsL[ASPLIT ? 128 * 64 : 8];
    __shared__ alignas(16) __bf16 BldsH[128 * 64];
    __shared__ alignas(16) __bf16 BldsL[128 * 64];

    const int tid  = threadIdx.x;
    const int lane = tid & 63;
    const int wave = tid >> 6;
    const int lr   = lane & 15;
    const int lg   = lane >> 4;
    const int m0   = blockIdx.y * 128;
    const int n0   = blockIdx.x * 128;
    const int wm   = (wave >> 1) * 64;
    const int wn   = (wave & 1) * 64;
    const int bn   = tid & 127;
    const int bkh  = (tid >> 7) * 32;

    f32x4 acc[4][4] = {};
    const float* bsrc0 = Bw + (size_t)bkh * N + n0 + bn;

    for (int k0 = 0; k0 < K; k0 += 64) {
        #pragma unroll
        for (int c = 0; c < 4; ++c) {
            int li  = c * 256 + tid;
            int row = li >> 3;
            int lcb = ((li & 7) << 4) ^ ((row & 7) << 4);
            size_t goff = (size_t)(m0 + row) * K + k0 + (lcb >> 1);
            size_t loff = (size_t)(c * 256 + wave * 64) * 16;
            gload_lds16(Ahi + goff, (char*)AldsH + loff);
            if constexpr (ASPLIT)
                gload_lds16(Alo + goff, (char*)AldsL + loff);
        }
        const float* bs = bsrc0 + (size_t)k0 * N;
        #pragma unroll
        for (int c = 0; c < 4; ++c) {
            bf16x8 ph, plv;
            #pragma unroll
            for (int j = 0; j < 8; ++j) {
                HL e = split2(bs[(size_t)(c * 8 + j) * N]);
                ph[j] = e.h;
                plv[j] = e.l;
            }
            int pcb = (bkh * 2 + c * 16) ^ ((bn & 7) << 4);
            *(bf16x8*)((char*)BldsH + bn * 128 + pcb) = ph;
            *(bf16x8*)((char*)BldsL + bn * 128 + pcb) = plv;
        }
        __syncthreads();

        bf16x8 ah[2][4], al[2][4], bh[2][4], bl[2][4];
        #pragma unroll
        for (int ks = 0; ks < 2; ++ks) {
            #pragma unroll
            for (int i = 0; i < 4; ++i) {
                int ra = wm + i * 16 + lr;
                int pa = (ks * 64 + lg * 16) ^ ((ra & 7) << 4);
                ah[ks][i] = *(const bf16x8*)((const char*)AldsH + ra * 128 + pa);
                if constexpr (ASPLIT)
                    al[ks][i] = *(const bf16x8*)((const char*)AldsL + ra * 128 + pa);
                int rb = wn + i * 16 + lr;
                int pb = (ks * 64 + lg * 16) ^ ((rb & 7) << 4);
                bh[ks][i] = *(const bf16x8*)((const char*)BldsH + rb * 128 + pb);
                bl[ks][i] = *(const bf16x8*)((const char*)BldsL + rb * 128 + pb);
            }
        }
        #pragma unroll
        for (int ks = 0; ks < 2; ++ks)
            #pragma unroll
            for (int mi = 0; mi < 4; ++mi)
                #pragma unroll
                for (int ni = 0; ni < 4; ++ni) {
                    acc[mi][ni] = mfma16(ah[ks][mi], bh[ks][ni], acc[mi][ni]);
                    if constexpr (ASPLIT)
                        acc[mi][ni] = mfma16(al[ks][mi], bh[ks][ni], acc[mi][ni]);
                    acc[mi][ni] = mfma16(ah[ks][mi], bl[ks][ni], acc[mi][ni]);
                }
        __syncthreads();
    }

    #pragma unroll
    for (int ni = 0; ni < 4; ++ni) {
        int col = n0 + wn + ni * 16 + lr;
        float bv = bias[col];
        #pragma unroll
        for (int mi = 0; mi < 4; ++mi) {
            int rowb = m0 + wm + mi * 16 + lg * 4;
            #pragma unroll
            for (int r = 0; r < 4; ++r) {
                float v = acc[mi][ni][r] + bv;
                if (RELU) v = fmaxf(v, 0.f);
                size_t idx = (size_t)(rowb + r) * N + col;
                if constexpr (OUTMODE == 0) ((float*)out)[idx] = v;
                else                        ((__bf16*)out)[idx] = (__bf16)v;
            }
        }
    }
}

// ---------------------------------------------------------------------------
// Fused QKV GEMM: one dispatch computes q,k,v. Head-major outputs [B,NH,S,HD].
// LAYER0: A split (3 MFMA) + q,k written hi+lo. Else plain A (2 MFMA), plain out.
// grid.x = 24: widx = gx>>3 selects W; n0 = (gx&7)*128.
// ---------------------------------------------------------------------------
struct QKVArgs {
    const float *Wq, *Wk, *Wv, *bq, *bk, *bv;
    __bf16 *qh, *ql, *kh, *kl, *vv;
};

template<int LAYER0>
__global__ __launch_bounds__(256) void qkv_kernel(
    const __bf16* __restrict__ Ahi, const __bf16* __restrict__ Alo, QKVArgs a)
{
    constexpr int N = Hc, K = Hc;
    __shared__ alignas(16) __bf16 AldsH[128 * 64];
    __shared__ alignas(16) __bf16 AldsL[LAYER0 ? 128 * 64 : 8];
    __shared__ alignas(16) __bf16 BldsH[128 * 64];
    __shared__ alignas(16) __bf16 BldsL[128 * 64];

    const int tid  = threadIdx.x;
    const int lane = tid & 63;
    const int wave = tid >> 6;
    const int lr   = lane & 15;
    const int lg   = lane >> 4;
    const int gx   = blockIdx.x;
    const int widx = gx >> 3;
    const int n0   = (gx & 7) * 128;
    const int m0   = blockIdx.y * 128;
    const int wm   = (wave >> 1) * 64;
    const int wn   = (wave & 1) * 64;
    const int bn   = tid & 127;
    const int bkh  = (tid >> 7) * 32;

    const float* Bw   = (widx == 0) ? a.Wq : (widx == 1) ? a.Wk : a.Wv;
    const float* bias = (widx == 0) ? a.bq : (widx == 1) ? a.bk : a.bv;

    f32x4 acc[4][4] = {};
    const float* bsrc0 = Bw + (size_t)bkh * N + n0 + bn;

    for (int k0 = 0; k0 < K; k0 += 64) {
        #pragma unroll
        for (int c = 0; c < 4; ++c) {
            int li  = c * 256 + tid;
            int row = li >> 3;
            int lcb = ((li & 7) << 4) ^ ((row & 7) << 4);
            size_t goff = (size_t)(m0 + row) * K + k0 + (lcb >> 1);
            size_t loff = (size_t)(c * 256 + wave * 64) * 16;
            gload_lds16(Ahi + goff, (char*)AldsH + loff);
            if constexpr (LAYER0)
                gload_lds16(Alo + goff, (char*)AldsL + loff);
        }
        const float* bs = bsrc0 + (size_t)k0 * N;
        #pragma unroll
        for (int c = 0; c < 4; ++c) {
            bf16x8 ph, plv;
            #pragma unroll
            for (int j = 0; j < 8; ++j) {
                HL e = split2(bs[(size_t)(c * 8 + j) * N]);
                ph[j] = e.h;
                plv[j] = e.l;
            }
            int pcb = (bkh * 2 + c * 16) ^ ((bn & 7) << 4);
            *(bf16x8*)((char*)BldsH + bn * 128 + pcb) = ph;
            *(bf16x8*)((char*)BldsL + bn * 128 + pcb) = plv;
        }
        __syncthreads();

        bf16x8 ah[2][4], al[2][4], bh[2][4], bl[2][4];
        #pragma unroll
        for (int ks = 0; ks < 2; ++ks) {
            #pragma unroll
            for (int i = 0; i < 4; ++i) {
                int ra = wm + i * 16 + lr;
                int pa = (ks * 64 + lg * 16) ^ ((ra & 7) << 4);
                ah[ks][i] = *(const bf16x8*)((const char*)AldsH + ra * 128 + pa);
                if constexpr (LAYER0)
                    al[ks][i] = *(const bf16x8*)((const char*)AldsL + ra * 128 + pa);
                int rb = wn + i * 16 + lr;
                int pb = (ks * 64 + lg * 16) ^ ((rb & 7) << 4);
                bh[ks][i] = *(const bf16x8*)((const char*)BldsH + rb * 128 + pb);
                bl[ks][i] = *(const bf16x8*)((const char*)BldsL + rb * 128 + pb);
            }
        }
        #pragma unroll
        for (int ks = 0; ks < 2; ++ks)
            #pragma unroll
            for (int mi = 0; mi < 4; ++mi)
                #pragma unroll
                for (int ni = 0; ni < 4; ++ni) {
                    acc[mi][ni] = mfma16(ah[ks][mi], bh[ks][ni], acc[mi][ni]);
                    if constexpr (LAYER0)
                        acc[mi][ni] = mfma16(al[ks][mi], bh[ks][ni], acc[mi][ni]);
                    acc[mi][ni] = mfma16(ah[ks][mi], bl[ks][ni], acc[mi][ni]);
                }
        __syncthreads();
    }

    // epilogue: head-major store [B,NH,S,HD]
    __bf16* outh = (widx == 0) ? a.qh : (widx == 1) ? a.kh : a.vv;
    __bf16* outl = (widx == 0) ? a.ql : a.kl;
    #pragma unroll
    for (int ni = 0; ni < 4; ++ni) {
        int col = n0 + wn + ni * 16 + lr;
        float bv = bias[col];
        int hh = col >> 6, d = col & 63;
        #pragma unroll
        for (int mi = 0; mi < 4; ++mi) {
            int rowb = m0 + wm + mi * 16 + lg * 4;
            #pragma unroll
            for (int r = 0; r < 4; ++r) {
                int row = rowb + r;
                int bb = row >> 11, s = row & (Sc - 1);
                size_t idx = ((size_t)(bb * NHc + hh) * Sc + s) * HDc + d;
                float v = acc[mi][ni][r] + bv;
                if (LAYER0 && widx < 2) {
                    HL e = split2(v);
                    outh[idx] = e.h;
                    outl[idx] = e.l;
                } else {
                    outh[idx] = (__bf16)v;
                }
            }
        }
    }
}

// ---------------------------------------------------------------------------
// Flash attention. q/k/v head-major [B,NH,S,HD]. Block = 4 waves, 64 q-rows,
// 64 keys/tile. K staged via global_load_lds (swizzled); V transposed into
// LDS VT[d][key] with both-sides XOR swizzle; PV B-frags = ds_read_b128.
// QKSPLIT: layer-0 hi+lo q,k (6 MFMA QK^T). Output ctx row-major [B,S,H] bf16.
// ---------------------------------------------------------------------------
template<int QKSPLIT>
__global__ __launch_bounds__(256) void attn_kernel(
    const __bf16* __restrict__ Qh, const __bf16* __restrict__ Ql,
    const __bf16* __restrict__ Kh, const __bf16* __restrict__ Kl,
    const __bf16* __restrict__ V, __bf16* __restrict__ O)
{
    __shared__ alignas(16) __bf16 KldsH[64 * 64];
    __shared__ alignas(16) __bf16 KldsL[QKSPLIT ? 64 * 64 : 8];
    __shared__ alignas(16) __bf16 VT[64 * 64];
    __shared__ alignas(16) char plds[4][2048];

    const int tid = threadIdx.x;
    const int lane = tid & 63, wave = tid >> 6;
    const int lr = lane & 15, lg = lane >> 4;
    const int h = blockIdx.y, b = blockIdx.z;
    const int q0 = blockIdx.x * 64 + wave * 16;
    char* pl = plds[wave];

    const size_t headoff = ((size_t)b * NHc + h) * Sc * HDc;
    const __bf16* Qb = Qh + headoff;
    const __bf16* Kb = Kh + headoff;
    const __bf16* Vb = V  + headoff;

    const size_t qrow = (size_t)(q0 + lr) * HDc;
    bf16x8 qf0 = *(const bf16x8*)(Qb + qrow + lg * 8);
    bf16x8 qf1 = *(const bf16x8*)(Qb + qrow + 32 + lg * 8);
    bf16x8 qlo0, qlo1;
    if constexpr (QKSPLIT) {
        const __bf16* Qlb = Ql + headoff;
        qlo0 = *(const bf16x8*)(Qlb + qrow + lg * 8);
        qlo1 = *(const bf16x8*)(Qlb + qrow + 32 + lg * 8);
    }

    // staging maps
    const int srow = tid >> 3;                       // K-staging row (c=0 half)
    const int slcb = ((tid & 7) << 4) ^ ((srow & 7) << 4);
    const int vkey = tid >> 2, vdq = tid & 3;        // V-staging

    f32x4 o[4] = {};
    float m = -1e30f, lsum = 0.f;

    for (int kt = 0; kt < Sc / 64; ++kt) {
        __syncthreads();   // prior tile's LDS reads done
        // ---- K tile (and Kl) via global_load_lds ----
        #pragma unroll
        for (int c = 0; c < 2; ++c) {
            int li  = c * 256 + tid;
            int row = li >> 3;
            int lcb = ((li & 7) << 4) ^ ((row & 7) << 4);
            size_t goff = (size_t)(kt * 64 + row) * HDc + (lcb >> 1);
            size_t loff = (size_t)(c * 256 + wave * 64) * 16;
            gload_lds16(Kb + goff, (char*)KldsH + loff);
            if constexpr (QKSPLIT)
                gload_lds16(Kl + headoff + goff, (char*)KldsL + loff);
        }
        // ---- V tile transposed into VT[d][key], swizzled ----
        {
            const __bf16* vs = Vb + (size_t)(kt * 64 + vkey) * HDc + vdq * 16;
            bf16x8 v0 = *(const bf16x8*)vs;
            bf16x8 v1 = *(const bf16x8*)(vs + 8);
            #pragma unroll
            for (int j = 0; j < 8; ++j) {
                int d = vdq * 16 + j;
                int sw = (d & 7) ^ ((vdq & 3) << 1);
                int addr = d * 128 + (((vkey >> 3) ^ sw) << 4) + (vkey & 7) * 2;
                *(__bf16*)((char*)VT + addr) = v0[j];
            }
            #pragma unroll
            for (int j = 0; j < 8; ++j) {
                int d = vdq * 16 + 8 + j;
                int sw = (d & 7) ^ ((vdq & 3) << 1);
                int addr = d * 128 + (((vkey >> 3) ^ sw) << 4) + (vkey & 7) * 2;
                *(__bf16*)((char*)VT + addr) = v1[j];
            }
        }
        __syncthreads();   // staging complete (vmcnt+lgkmcnt drained)

        // ---- QK^T ----
        f32x4 s[4];
        #pragma unroll
        for (int kg = 0; kg < 4; ++kg) {
            int ra = kg * 16 + lr;
            int pa0 = (lg * 16) ^ ((ra & 7) << 4);
            int pa1 = (64 + lg * 16) ^ ((ra & 7) << 4);
            bf16x8 kf0 = *(const bf16x8*)((const char*)KldsH + ra * 128 + pa0);
            bf16x8 kf1 = *(const bf16x8*)((const char*)KldsH + ra * 128 + pa1);
            f32x4 t = {};
            t = mfma16(kf0, qf0, t);
            t = mfma16(kf1, qf1, t);
            if constexpr (QKSPLIT) {
                bf16x8 kg0 = *(const bf16x8*)((const char*)KldsL + ra * 128 + pa0);
                bf16x8 kg1 = *(const bf16x8*)((const char*)KldsL + ra * 128 + pa1);
                t = mfma16(kg0, qf0, t);
                t = mfma16(kg1, qf1, t);
                t = mfma16(kf0, qlo0, t);
                t = mfma16(kf1, qlo1, t);
            }
            s[kg] = t;
        }
        // ---- online softmax (per q-row = lr, keys spread over lg,r) ----
        float mt = -1e30f;
        #pragma unroll
        for (int kg = 0; kg < 4; ++kg)
            #pragma unroll
            for (int r = 0; r < 4; ++r) {
                s[kg][r] *= 0.125f;
                mt = fmaxf(mt, s[kg][r]);
            }
        mt = fmaxf(mt, __shfl_xor(mt, 16));
        mt = fmaxf(mt, __shfl_xor(mt, 32));
        float mnew = fmaxf(m, mt);
        float fac = __expf(m - mnew);
        m = mnew;
        float ps = 0.f;
        #pragma unroll
        for (int kg = 0; kg < 4; ++kg)
            #pragma unroll
            for (int r = 0; r < 4; ++r) {
                float p = __expf(s[kg][r] - mnew);
                ps += p;
                s[kg][r] = p;
            }
        ps += __shfl_xor(ps, 16);
        ps += __shfl_xor(ps, 32);
        lsum = lsum * fac + ps;
        #pragma unroll
        for (int r = 0; r < 4; ++r) {
            float fr = __shfl(fac, (lg << 4) | (lg * 4 + r));
            #pragma unroll
            for (int nd = 0; nd < 4; ++nd) o[nd][r] *= fr;
        }
        // ---- P -> per-wave LDS ----
        #pragma unroll
        for (int kg = 0; kg < 4; ++kg)
            #pragma unroll
            for (int r = 0; r < 4; ++r) {
                int key = kg * 16 + lg * 4 + r;
                int pa  = key * 32 + ((lr * 2) ^ (((key >> 2) & 3) << 3));
                *(__bf16*)(pl + pa) = (__bf16)s[kg][r];
            }
        // ---- PV: paf from P-LDS, vbf from VT (vector reads) ----
        #pragma unroll
        for (int kh2 = 0; kh2 < 2; ++kh2) {
            bf16x8 paf;
            #pragma unroll
            for (int j = 0; j < 8; ++j) {
                int key = kh2 * 32 + lg * 8 + j;
                int pa  = key * 32 + ((lr * 2) ^ (((key >> 2) & 3) << 3));
                paf[j] = *(const __bf16*)(pl + pa);
            }
            #pragma unroll
            for (int nd = 0; nd < 4; ++nd) {
                int d  = nd * 16 + lr;
                int sw = (d & 7) ^ ((nd & 3) << 1);
                int slot = (kh2 * 4 + lg) ^ sw;
                bf16x8 vbf = *(const bf16x8*)((const char*)VT + d * 128 + slot * 16);
                o[nd] = mfma16(paf, vbf, o[nd]);
            }
        }
    }
    // ---- epilogue: row-major ctx [B,S,H] ----
    #pragma unroll
    for (int r = 0; r < 4; ++r) {
        float lv  = __shfl(lsum, (lg << 4) | (lg * 4 + r));
        float inv = 1.f / lv;
        size_t orow = ((size_t)b * Sc + q0 + lg * 4 + r) * Hc + h * HDc;
        #pragma unroll
        for (int nd = 0; nd < 4; ++nd)
            O[orow + nd * 16 + lr] = (__bf16)(o[nd][r] * inv);
    }
}

// ---------------------------------------------------------------------------
// Fused residual + LayerNorm: f32 master + bf16 copy
// ---------------------------------------------------------------------------
__global__ __launch_bounds__(256) void ln_kernel(
    const float* __restrict__ xr, const float* __restrict__ y,
    const float* __restrict__ g, const float* __restrict__ beta,
    float* __restrict__ of, __bf16* __restrict__ oh)
{
    __shared__ float red[2][4];
    const int row = blockIdx.x, t = threadIdx.x;
    const int lane = t & 63, wave = t >> 6;
    const int idx = row * 256 + t;
    float4 a = ((const float4*)xr)[idx];
    float4 c = ((const float4*)y)[idx];
    float4 v;
    v.x = a.x + c.x; v.y = a.y + c.y; v.z = a.z + c.z; v.w = a.w + c.w;
    float s1 = v.x + v.y + v.z + v.w;
    float s2 = v.x * v.x + v.y * v.y + v.z * v.z + v.w * v.w;
    #pragma unroll
    for (int off = 1; off < 64; off <<= 1) {
        s1 += __shfl_xor(s1, off);
        s2 += __shfl_xor(s2, off);
    }
    if (lane == 0) { red[0][wave] = s1; red[1][wave] = s2; }
    __syncthreads();
    s1 = red[0][0] + red[0][1] + red[0][2] + red[0][3];
    s2 = red[1][0] + red[1][1] + red[1][2] + red[1][3];
    const float mu   = s1 * (1.f / Hc);
    const float var  = s2 * (1.f / Hc) - mu * mu;
    const float rstd = rsqrtf(var + EPSc);
    float4 gg = ((const float4*)g)[t];
    float4 bb = ((const float4*)beta)[t];
    float4 r;
    r.x = (v.x - mu) * rstd * gg.x + bb.x;
    r.y = (v.y - mu) * rstd * gg.y + bb.y;
    r.z = (v.z - mu) * rstd * gg.z + bb.z;
    r.w = (v.w - mu) * rstd * gg.w + bb.w;
    ((float4*)of)[idx] = r;
    bf16x4 hh = { (__bf16)r.x, (__bf16)r.y, (__bf16)r.z, (__bf16)r.w };
    ((bf16x4*)oh)[idx] = hh;
}

// ---------------------------------------------------------------------------
extern "C" void kernel_launch(void* const* d_in, const int* in_sizes, int n_in,
                              void* d_out, int out_size, void* d_ws, size_t ws_size,
                              hipStream_t stream)
{
    const float* inp = (const float*)d_in[0];
    const float* pos = (const float*)d_in[1];
    const float* Wq  = (const float*)d_in[2];
    const float* bq  = (const float*)d_in[3];
    const float* Wk  = (const float*)d_in[4];
    const float* bk  = (const float*)d_in[5];
    const float* Wv  = (const float*)d_in[6];
    const float* bv  = (const float*)d_in[7];
    const float* Wo  = (const float*)d_in[8];
    const float* bo  = (const float*)d_in[9];
    const float* lng = (const float*)d_in[10];
    const float* lnb = (const float*)d_in[11];
    const float* W1  = (const float*)d_in[12];
    const float* b1  = (const float*)d_in[13];
    const float* W2  = (const float*)d_in[14];
    const float* b2  = (const float*)d_in[15];

    char* ws = (char*)d_ws;
    const size_t MB = 1u << 20;
    float*  src_f = (float*)(ws);              // 16 MB
    __bf16* src_h = (__bf16*)(ws + 16 * MB);   //  8 MB
    __bf16* src_l = (__bf16*)(ws + 24 * MB);   //  8 MB
    __bf16* qh    = (__bf16*)(ws + 32 * MB);   //  8 MB  (head-major)
    __bf16* ql    = (__bf16*)(ws + 40 * MB);
    __bf16* kh    = (__bf16*)(ws + 48 * MB);
    __bf16* kl    = (__bf16*)(ws + 56 * MB);
    __bf16* vv    = (__bf16*)(ws + 64 * MB);
    __bf16* ctx   = (__bf16*)(ws + 72 * MB);   //  8 MB  (row-major)
    __bf16* h1    = (__bf16*)(ws + 32 * MB);   // 32 MB alias over qh..kl
    float*  tmp   = (float*)(ws + 88 * MB);    // 16 MB ; total 104 MB

    const int M = Bc * Sc;  // 4096

    embed_kernel<<<2048, 256, 0, stream>>>(inp, pos, src_f, src_h, src_l);

    for (int l = 0; l < Lc; ++l) {
        const size_t wHH = (size_t)l * Hc * Hc;
        const size_t wH  = (size_t)l * Hc;
        QKVArgs qa = { Wq + wHH, Wk + wHH, Wv + wHH, bq + wH, bk + wH, bv + wH,
                       qh, ql, kh, kl, vv };
        if (l == 0) {
            qkv_kernel<1><<<dim3(24, 32), 256, 0, stream>>>(src_h, src_l, qa);
            attn_kernel<1><<<dim3(32, 16, 2), 256, 0, stream>>>(qh, ql, kh, kl, vv, ctx);
        } else {
            qkv_kernel<0><<<dim3(24, 32), 256, 0, stream>>>(src_h, nullptr, qa);
            attn_kernel<0><<<dim3(32, 16, 2), 256, 0, stream>>>(qh, nullptr, kh, nullptr, vv, ctx);
        }
        gemm_kernel<0, 0, false><<<dim3(8, 32), 256, 0, stream>>>(
            ctx, nullptr, Wo + wHH, bo + wH, tmp, M, Hc, Hc);
        ln_kernel<<<M, 256, 0, stream>>>(src_f, tmp, lng + wH, lnb + wH, src_f, src_h);
        gemm_kernel<0, 1, true><<<dim3(32, 32), 256, 0, stream>>>(
            src_h, nullptr, W1 + (size_t)l * Hc * PFc, b1 + (size_t)l * PFc, h1, M, PFc, Hc);
        gemm_kernel<0, 0, false><<<dim3(8, 32), 256, 0, stream>>>(
            h1, nullptr, W2 + (size_t)l * PFc * Hc, b2 + wH, tmp, M, Hc, PFc);
        float* dst = (l == Lc - 1) ? (float*)d_out : src_f;
        ln_kernel<<<M, 256, 0, stream>>>(src_f, tmp, lng + wH, lnb + wH, dst, src_h);
    }
}

// Round 5
// 2060.416 us; speedup vs baseline: 2.5855x; 1.3064x over previous
//
#include <hip/hip_runtime.h>
#include <cstdint>

constexpr int Bc = 2, Sc = 2048, Hc = 1024, NHc = 16, HDc = 64, PFc = 4096, Lc = 6;
constexpr float EPSc = 1e-5f;

using f32x4  = __attribute__((ext_vector_type(4))) float;
using bf16x8 = __attribute__((ext_vector_type(8))) __bf16;
using bf16x4 = __attribute__((ext_vector_type(4))) __bf16;

__device__ __forceinline__ f32x4 mfma16(bf16x8 a, bf16x8 b, f32x4 c) {
    return __builtin_amdgcn_mfma_f32_16x16x32_bf16(a, b, c, 0, 0, 0);
}

__device__ __forceinline__ void gload_lds16(const void* g, void* l) {
    __builtin_amdgcn_global_load_lds(
        (__attribute__((address_space(1))) void*)(uintptr_t)g,
        (__attribute__((address_space(3))) void*)(uint32_t)(uintptr_t)l,
        16, 0, 0);
}

struct HL { __bf16 h, l; };
__device__ __forceinline__ HL split2(float v) {
    HL r;
    r.h = (__bf16)v;
    r.l = (__bf16)(v - (float)r.h);
    return r;
}

// ---------------------------------------------------------------------------
// Weight convert: in f32 [K][N] (per-layer stride K*N, z = layer) ->
// out bf16 [N][K]. 64x64 tiles via LDS.
// ---------------------------------------------------------------------------
__global__ __launch_bounds__(256) void wconv_kernel(
    const float* __restrict__ in, __bf16* __restrict__ out, int K, int N)
{
    __shared__ float tile[64][65];
    const int t = threadIdx.x;
    const size_t lstride = (size_t)K * N;
    const float* ip = in + (size_t)blockIdx.z * lstride;
    __bf16* op = out + (size_t)blockIdx.z * lstride;
    const int n0 = blockIdx.x * 64, k0 = blockIdx.y * 64;
    #pragma unroll
    for (int c = 0; c < 4; ++c) {
        int idx = c * 256 + t;           // [0,1024)
        int row = idx >> 4;              // k within tile
        int c4  = idx & 15;
        float4 v = *(const float4*)(ip + (size_t)(k0 + row) * N + n0 + c4 * 4);
        tile[row][c4 * 4 + 0] = v.x; tile[row][c4 * 4 + 1] = v.y;
        tile[row][c4 * 4 + 2] = v.z; tile[row][c4 * 4 + 3] = v.w;
    }
    __syncthreads();
    #pragma unroll
    for (int c = 0; c < 4; ++c) {
        int idx = c * 256 + t;
        int n  = idx >> 4;
        int k4 = idx & 15;
        bf16x4 hh = { (__bf16)tile[k4 * 4 + 0][n], (__bf16)tile[k4 * 4 + 1][n],
                      (__bf16)tile[k4 * 4 + 2][n], (__bf16)tile[k4 * 4 + 3][n] };
        *(bf16x4*)(op + (size_t)(n0 + n) * K + k0 + k4 * 4) = hh;
    }
}

// ---------------------------------------------------------------------------
// Embed: src = in*32 + pos ; f32 master + split bf16 (layer-0 QKV needs split A)
// ---------------------------------------------------------------------------
__global__ __launch_bounds__(256) void embed_kernel(
    const float* __restrict__ in, const float* __restrict__ pos,
    float* __restrict__ sf, __bf16* __restrict__ sh, __bf16* __restrict__ sl)
{
    const int n4 = (Bc * Sc * Hc) / 4;
    const int pmask = (Sc * Hc / 4) - 1;
    for (int i = blockIdx.x * 256 + threadIdx.x; i < n4; i += gridDim.x * 256) {
        float4 a = ((const float4*)in)[i];
        float4 p = ((const float4*)pos)[i & pmask];
        float4 r;
        r.x = a.x * 32.f + p.x; r.y = a.y * 32.f + p.y;
        r.z = a.z * 32.f + p.z; r.w = a.w * 32.f + p.w;
        ((float4*)sf)[i] = r;
        HL e0 = split2(r.x), e1 = split2(r.y), e2 = split2(r.z), e3 = split2(r.w);
        bf16x4 hh = { e0.h, e1.h, e2.h, e3.h };
        bf16x4 ll = { e0.l, e1.l, e2.l, e3.l };
        ((bf16x4*)sh)[i] = hh;
        ((bf16x4*)sl)[i] = ll;
    }
}

// ---------------------------------------------------------------------------
// GEMM on pre-transposed bf16 weights: C = act(A @ W + bias), Wt [N][K] bf16.
// BM x 128 tile, BK=64, 4 waves. Both A and B staged via global_load_lds
// with pre-swizzled source. OUTMODE: 0=f32, 1=bf16.
// ---------------------------------------------------------------------------
template<int BM, int OUTMODE, bool RELU>
__global__ __launch_bounds__(256) void gemm_bt_kernel(
    const __bf16* __restrict__ A, const __bf16* __restrict__ Wt,
    const float* __restrict__ bias, void* __restrict__ out,
    int M, int N, int K)
{
    constexpr int MI = BM / 32;              // m-frags per wave
    __shared__ alignas(16) __bf16 Alds[BM * 64];
    __shared__ alignas(16) __bf16 Blds[128 * 64];

    const int tid = threadIdx.x, lane = tid & 63, wave = tid >> 6;
    const int lr = lane & 15, lg = lane >> 4;
    const int m0 = blockIdx.y * BM, n0 = blockIdx.x * 128;
    const int wm = (wave >> 1) * (BM / 2), wn = (wave & 1) * 64;

    f32x4 acc[MI][4] = {};

    for (int k0 = 0; k0 < K; k0 += 64) {
        #pragma unroll
        for (int c = 0; c < BM / 32; ++c) {          // A: BM*8 chunks
            int li = c * 256 + tid;
            int row = li >> 3;
            int lcb = ((li & 7) << 4) ^ ((row & 7) << 4);
            gload_lds16(A + (size_t)(m0 + row) * K + k0 + (lcb >> 1),
                        (char*)Alds + (size_t)(c * 256 + wave * 64) * 16);
        }
        #pragma unroll
        for (int c = 0; c < 4; ++c) {                // B: 128*8 chunks
            int li = c * 256 + tid;
            int row = li >> 3;
            int lcb = ((li & 7) << 4) ^ ((row & 7) << 4);
            gload_lds16(Wt + (size_t)(n0 + row) * K + k0 + (lcb >> 1),
                        (char*)Blds + (size_t)(c * 256 + wave * 64) * 16);
        }
        __syncthreads();

        bf16x8 af[2][MI], bfr[2][4];
        #pragma unroll
        for (int ks = 0; ks < 2; ++ks) {
            #pragma unroll
            for (int i = 0; i < MI; ++i) {
                int ra = wm + i * 16 + lr;
                int pa = (ks * 64 + lg * 16) ^ ((ra & 7) << 4);
                af[ks][i] = *(const bf16x8*)((const char*)Alds + ra * 128 + pa);
            }
            #pragma unroll
            for (int i = 0; i < 4; ++i) {
                int rb = wn + i * 16 + lr;
                int pb = (ks * 64 + lg * 16) ^ ((rb & 7) << 4);
                bfr[ks][i] = *(const bf16x8*)((const char*)Blds + rb * 128 + pb);
            }
        }
        #pragma unroll
        for (int ks = 0; ks < 2; ++ks)
            #pragma unroll
            for (int mi = 0; mi < MI; ++mi)
                #pragma unroll
                for (int ni = 0; ni < 4; ++ni)
                    acc[mi][ni] = mfma16(af[ks][mi], bfr[ks][ni], acc[mi][ni]);
        __syncthreads();
    }

    #pragma unroll
    for (int ni = 0; ni < 4; ++ni) {
        int col = n0 + wn + ni * 16 + lr;
        float bv = bias[col];
        #pragma unroll
        for (int mi = 0; mi < MI; ++mi) {
            int rowb = m0 + wm + mi * 16 + lg * 4;
            #pragma unroll
            for (int r = 0; r < 4; ++r) {
                float v = acc[mi][ni][r] + bv;
                if (RELU) v = fmaxf(v, 0.f);
                size_t idx = (size_t)(rowb + r) * N + col;
                if constexpr (OUTMODE == 0) ((float*)out)[idx] = v;
                else                        ((__bf16*)out)[idx] = (__bf16)v;
            }
        }
    }
}

// ---------------------------------------------------------------------------
// Fused QKV on pre-transposed bf16 weights (layers >= 1). Head-major out.
// grid.x = 24: widx = gx>>3 selects W; n0 = (gx&7)*128.
// ---------------------------------------------------------------------------
struct QKVBT {
    const __bf16 *wq, *wk, *wv;
    const float *bq, *bk, *bv;
    __bf16 *q, *k, *v;
};

__global__ __launch_bounds__(256) void qkv_bt_kernel(
    const __bf16* __restrict__ A, QKVBT a)
{
    constexpr int N = Hc, K = Hc;
    __shared__ alignas(16) __bf16 Alds[128 * 64];
    __shared__ alignas(16) __bf16 Blds[128 * 64];

    const int tid = threadIdx.x, lane = tid & 63, wave = tid >> 6;
    const int lr = lane & 15, lg = lane >> 4;
    const int gx = blockIdx.x;
    const int widx = gx >> 3;
    const int n0 = (gx & 7) * 128;
    const int m0 = blockIdx.y * 128;
    const int wm = (wave >> 1) * 64, wn = (wave & 1) * 64;

    const __bf16* Wt  = (widx == 0) ? a.wq : (widx == 1) ? a.wk : a.wv;
    const float* bias = (widx == 0) ? a.bq : (widx == 1) ? a.bk : a.bv;

    f32x4 acc[4][4] = {};

    for (int k0 = 0; k0 < K; k0 += 64) {
        #pragma unroll
        for (int c = 0; c < 4; ++c) {
            int li = c * 256 + tid;
            int row = li >> 3;
            int lcb = ((li & 7) << 4) ^ ((row & 7) << 4);
            gload_lds16(A + (size_t)(m0 + row) * K + k0 + (lcb >> 1),
                        (char*)Alds + (size_t)(c * 256 + wave * 64) * 16);
            gload_lds16(Wt + (size_t)(n0 + row) * K + k0 + (lcb >> 1),
                        (char*)Blds + (size_t)(c * 256 + wave * 64) * 16);
        }
        __syncthreads();

        bf16x8 af[2][4], bfr[2][4];
        #pragma unroll
        for (int ks = 0; ks < 2; ++ks) {
            #pragma unroll
            for (int i = 0; i < 4; ++i) {
                int ra = wm + i * 16 + lr;
                int pa = (ks * 64 + lg * 16) ^ ((ra & 7) << 4);
                af[ks][i] = *(const bf16x8*)((const char*)Alds + ra * 128 + pa);
                int rb = wn + i * 16 + lr;
                int pb = (ks * 64 + lg * 16) ^ ((rb & 7) << 4);
                bfr[ks][i] = *(const bf16x8*)((const char*)Blds + rb * 128 + pb);
            }
        }
        #pragma unroll
        for (int ks = 0; ks < 2; ++ks)
            #pragma unroll
            for (int mi = 0; mi < 4; ++mi)
                #pragma unroll
                for (int ni = 0; ni < 4; ++ni)
                    acc[mi][ni] = mfma16(af[ks][mi], bfr[ks][ni], acc[mi][ni]);
        __syncthreads();
    }

    __bf16* outp = (widx == 0) ? a.q : (widx == 1) ? a.k : a.v;
    #pragma unroll
    for (int ni = 0; ni < 4; ++ni) {
        int col = n0 + wn + ni * 16 + lr;
        float bv = bias[col];
        int hh = col >> 6, d = col & 63;
        #pragma unroll
        for (int mi = 0; mi < 4; ++mi) {
            int rowb = m0 + wm + mi * 16 + lg * 4;
            #pragma unroll
            for (int r = 0; r < 4; ++r) {
                int row = rowb + r;
                int bb = row >> 11, s = row & (Sc - 1);
                outp[((size_t)(bb * NHc + hh) * Sc + s) * HDc + d] =
                    (__bf16)(acc[mi][ni][r] + bv);
            }
        }
    }
}

// ---------------------------------------------------------------------------
// Layer-0 QKV (full split precision, f32 weights). Head-major out, q/k hi+lo.
// ---------------------------------------------------------------------------
struct QKVArgs {
    const float *Wq, *Wk, *Wv, *bq, *bk, *bv;
    __bf16 *qh, *ql, *kh, *kl, *vv;
};

__global__ __launch_bounds__(256) void qkv0_kernel(
    const __bf16* __restrict__ Ahi, const __bf16* __restrict__ Alo, QKVArgs a)
{
    constexpr int N = Hc, K = Hc;
    __shared__ alignas(16) __bf16 AldsH[128 * 64];
    __shared__ alignas(16) __bf16 AldsL[128 * 64];
    __shared__ alignas(16) __bf16 BldsH[128 * 64];
    __shared__ alignas(16) __bf16 BldsL[128 * 64];

    const int tid  = threadIdx.x;
    const int lane = tid & 63;
    const int wave = tid >> 6;
    const int lr   = lane & 15;
    const int lg   = lane >> 4;
    const int gx   = blockIdx.x;
    const int widx = gx >> 3;
    const int n0   = (gx & 7) * 128;
    const int m0   = blockIdx.y * 128;
    const int wm   = (wave >> 1) * 64;
    const int wn   = (wave & 1) * 64;
    const int bn   = tid & 127;
    const int bkh  = (tid >> 7) * 32;

    const float* Bw   = (widx == 0) ? a.Wq : (widx == 1) ? a.Wk : a.Wv;
    const float* bias = (widx == 0) ? a.bq : (widx == 1) ? a.bk : a.bv;

    f32x4 acc[4][4] = {};
    const float* bsrc0 = Bw + (size_t)bkh * N + n0 + bn;

    for (int k0 = 0; k0 < K; k0 += 64) {
        #pragma unroll
        for (int c = 0; c < 4; ++c) {
            int li  = c * 256 + tid;
            int row = li >> 3;
            int lcb = ((li & 7) << 4) ^ ((row & 7) << 4);
            size_t goff = (size_t)(m0 + row) * K + k0 + (lcb >> 1);
            size_t loff = (size_t)(c * 256 + wave * 64) * 16;
            gload_lds16(Ahi + goff, (char*)AldsH + loff);
            gload_lds16(Alo + goff, (char*)AldsL + loff);
        }
        const float* bs = bsrc0 + (size_t)k0 * N;
        #pragma unroll
        for (int c = 0; c < 4; ++c) {
            bf16x8 ph, plv;
            #pragma unroll
            for (int j = 0; j < 8; ++j) {
                HL e = split2(bs[(size_t)(c * 8 + j) * N]);
                ph[j] = e.h;
                plv[j] = e.l;
            }
            int pcb = (bkh * 2 + c * 16) ^ ((bn & 7) << 4);
            *(bf16x8*)((char*)BldsH + bn * 128 + pcb) = ph;
            *(bf16x8*)((char*)BldsL + bn * 128 + pcb) = plv;
        }
        __syncthreads();

        bf16x8 ah[2][4], al[2][4], bh[2][4], bl[2][4];
        #pragma unroll
        for (int ks = 0; ks < 2; ++ks) {
            #pragma unroll
            for (int i = 0; i < 4; ++i) {
                int ra = wm + i * 16 + lr;
                int pa = (ks * 64 + lg * 16) ^ ((ra & 7) << 4);
                ah[ks][i] = *(const bf16x8*)((const char*)AldsH + ra * 128 + pa);
                al[ks][i] = *(const bf16x8*)((const char*)AldsL + ra * 128 + pa);
                int rb = wn + i * 16 + lr;
                int pb = (ks * 64 + lg * 16) ^ ((rb & 7) << 4);
                bh[ks][i] = *(const bf16x8*)((const char*)BldsH + rb * 128 + pb);
                bl[ks][i] = *(const bf16x8*)((const char*)BldsL + rb * 128 + pb);
            }
        }
        #pragma unroll
        for (int ks = 0; ks < 2; ++ks)
            #pragma unroll
            for (int mi = 0; mi < 4; ++mi)
                #pragma unroll
                for (int ni = 0; ni < 4; ++ni) {
                    acc[mi][ni] = mfma16(ah[ks][mi], bh[ks][ni], acc[mi][ni]);
                    acc[mi][ni] = mfma16(al[ks][mi], bh[ks][ni], acc[mi][ni]);
                    acc[mi][ni] = mfma16(ah[ks][mi], bl[ks][ni], acc[mi][ni]);
                }
        __syncthreads();
    }

    __bf16* outh = (widx == 0) ? a.qh : (widx == 1) ? a.kh : a.vv;
    __bf16* outl = (widx == 0) ? a.ql : a.kl;
    #pragma unroll
    for (int ni = 0; ni < 4; ++ni) {
        int col = n0 + wn + ni * 16 + lr;
        float bv = bias[col];
        int hh = col >> 6, d = col & 63;
        #pragma unroll
        for (int mi = 0; mi < 4; ++mi) {
            int rowb = m0 + wm + mi * 16 + lg * 4;
            #pragma unroll
            for (int r = 0; r < 4; ++r) {
                int row = rowb + r;
                int bb = row >> 11, s = row & (Sc - 1);
                size_t idx = ((size_t)(bb * NHc + hh) * Sc + s) * HDc + d;
                float v = acc[mi][ni][r] + bv;
                if (widx < 2) {
                    HL e = split2(v);
                    outh[idx] = e.h;
                    outl[idx] = e.l;
                } else {
                    outh[idx] = (__bf16)v;
                }
            }
        }
    }
}

// ---------------------------------------------------------------------------
// Flash attention. q/k/v head-major [B,NH,S,HD]. Block = 4 waves, 64 q-rows,
// 64 keys/tile. K via global_load_lds (swizzled); V transposed in LDS.
// ---------------------------------------------------------------------------
template<int QKSPLIT>
__global__ __launch_bounds__(256) void attn_kernel(
    const __bf16* __restrict__ Qh, const __bf16* __restrict__ Ql,
    const __bf16* __restrict__ Kh, const __bf16* __restrict__ Kl,
    const __bf16* __restrict__ V, __bf16* __restrict__ O)
{
    __shared__ alignas(16) __bf16 KldsH[64 * 64];
    __shared__ alignas(16) __bf16 KldsL[QKSPLIT ? 64 * 64 : 8];
    __shared__ alignas(16) __bf16 VT[64 * 64];
    __shared__ alignas(16) char plds[4][2048];

    const int tid = threadIdx.x;
    const int lane = tid & 63, wave = tid >> 6;
    const int lr = lane & 15, lg = lane >> 4;
    const int h = blockIdx.y, b = blockIdx.z;
    const int q0 = blockIdx.x * 64 + wave * 16;
    char* pl = plds[wave];

    const size_t headoff = ((size_t)b * NHc + h) * Sc * HDc;
    const __bf16* Qb = Qh + headoff;
    const __bf16* Kb = Kh + headoff;
    const __bf16* Vb = V  + headoff;

    const size_t qrow = (size_t)(q0 + lr) * HDc;
    bf16x8 qf0 = *(const bf16x8*)(Qb + qrow + lg * 8);
    bf16x8 qf1 = *(const bf16x8*)(Qb + qrow + 32 + lg * 8);
    bf16x8 qlo0, qlo1;
    if constexpr (QKSPLIT) {
        const __bf16* Qlb = Ql + headoff;
        qlo0 = *(const bf16x8*)(Qlb + qrow + lg * 8);
        qlo1 = *(const bf16x8*)(Qlb + qrow + 32 + lg * 8);
    }

    const int vkey = tid >> 2, vdq = tid & 3;

    f32x4 o[4] = {};
    float m = -1e30f, lsum = 0.f;

    for (int kt = 0; kt < Sc / 64; ++kt) {
        __syncthreads();
        #pragma unroll
        for (int c = 0; c < 2; ++c) {
            int li  = c * 256 + tid;
            int row = li >> 3;
            int lcb = ((li & 7) << 4) ^ ((row & 7) << 4);
            size_t goff = (size_t)(kt * 64 + row) * HDc + (lcb >> 1);
            size_t loff = (size_t)(c * 256 + wave * 64) * 16;
            gload_lds16(Kb + goff, (char*)KldsH + loff);
            if constexpr (QKSPLIT)
                gload_lds16(Kl + headoff + goff, (char*)KldsL + loff);
        }
        {
            const __bf16* vs = Vb + (size_t)(kt * 64 + vkey) * HDc + vdq * 16;
            bf16x8 v0 = *(const bf16x8*)vs;
            bf16x8 v1 = *(const bf16x8*)(vs + 8);
            #pragma unroll
            for (int j = 0; j < 8; ++j) {
                int d = vdq * 16 + j;
                int sw = (d & 7) ^ ((vdq & 3) << 1);
                int addr = d * 128 + (((vkey >> 3) ^ sw) << 4) + (vkey & 7) * 2;
                *(__bf16*)((char*)VT + addr) = v0[j];
            }
            #pragma unroll
            for (int j = 0; j < 8; ++j) {
                int d = vdq * 16 + 8 + j;
                int sw = (d & 7) ^ ((vdq & 3) << 1);
                int addr = d * 128 + (((vkey >> 3) ^ sw) << 4) + (vkey & 7) * 2;
                *(__bf16*)((char*)VT + addr) = v1[j];
            }
        }
        __syncthreads();

        f32x4 s[4];
        #pragma unroll
        for (int kg = 0; kg < 4; ++kg) {
            int ra = kg * 16 + lr;
            int pa0 = (lg * 16) ^ ((ra & 7) << 4);
            int pa1 = (64 + lg * 16) ^ ((ra & 7) << 4);
            bf16x8 kf0 = *(const bf16x8*)((const char*)KldsH + ra * 128 + pa0);
            bf16x8 kf1 = *(const bf16x8*)((const char*)KldsH + ra * 128 + pa1);
            f32x4 t = {};
            t = mfma16(kf0, qf0, t);
            t = mfma16(kf1, qf1, t);
            if constexpr (QKSPLIT) {
                bf16x8 kg0 = *(const bf16x8*)((const char*)KldsL + ra * 128 + pa0);
                bf16x8 kg1 = *(const bf16x8*)((const char*)KldsL + ra * 128 + pa1);
                t = mfma16(kg0, qf0, t);
                t = mfma16(kg1, qf1, t);
                t = mfma16(kf0, qlo0, t);
                t = mfma16(kf1, qlo1, t);
            }
            s[kg] = t;
        }
        float mt = -1e30f;
        #pragma unroll
        for (int kg = 0; kg < 4; ++kg)
            #pragma unroll
            for (int r = 0; r < 4; ++r) {
                s[kg][r] *= 0.125f;
                mt = fmaxf(mt, s[kg][r]);
            }
        mt = fmaxf(mt, __shfl_xor(mt, 16));
        mt = fmaxf(mt, __shfl_xor(mt, 32));
        float mnew = fmaxf(m, mt);
        float fac = __expf(m - mnew);
        m = mnew;
        float ps = 0.f;
        #pragma unroll
        for (int kg = 0; kg < 4; ++kg)
            #pragma unroll
            for (int r = 0; r < 4; ++r) {
                float p = __expf(s[kg][r] - mnew);
                ps += p;
                s[kg][r] = p;
            }
        ps += __shfl_xor(ps, 16);
        ps += __shfl_xor(ps, 32);
        lsum = lsum * fac + ps;
        #pragma unroll
        for (int r = 0; r < 4; ++r) {
            float fr = __shfl(fac, (lg << 4) | (lg * 4 + r));
            #pragma unroll
            for (int nd = 0; nd < 4; ++nd) o[nd][r] *= fr;
        }
        #pragma unroll
        for (int kg = 0; kg < 4; ++kg)
            #pragma unroll
            for (int r = 0; r < 4; ++r) {
                int key = kg * 16 + lg * 4 + r;
                int pa  = key * 32 + ((lr * 2) ^ (((key >> 2) & 3) << 3));
                *(__bf16*)(pl + pa) = (__bf16)s[kg][r];
            }
        #pragma unroll
        for (int kh2 = 0; kh2 < 2; ++kh2) {
            bf16x8 paf;
            #pragma unroll
            for (int j = 0; j < 8; ++j) {
                int key = kh2 * 32 + lg * 8 + j;
                int pa  = key * 32 + ((lr * 2) ^ (((key >> 2) & 3) << 3));
                paf[j] = *(const __bf16*)(pl + pa);
            }
            #pragma unroll
            for (int nd = 0; nd < 4; ++nd) {
                int d  = nd * 16 + lr;
                int sw = (d & 7) ^ ((nd & 3) << 1);
                int slot = (kh2 * 4 + lg) ^ sw;
                bf16x8 vbf = *(const bf16x8*)((const char*)VT + d * 128 + slot * 16);
                o[nd] = mfma16(paf, vbf, o[nd]);
            }
        }
    }
    #pragma unroll
    for (int r = 0; r < 4; ++r) {
        float lv  = __shfl(lsum, (lg << 4) | (lg * 4 + r));
        float inv = 1.f / lv;
        size_t orow = ((size_t)b * Sc + q0 + lg * 4 + r) * Hc + h * HDc;
        #pragma unroll
        for (int nd = 0; nd < 4; ++nd)
            O[orow + nd * 16 + lr] = (__bf16)(o[nd][r] * inv);
    }
}

// ---------------------------------------------------------------------------
// Fused residual + LayerNorm: f32 master + bf16 copy
// ---------------------------------------------------------------------------
__global__ __launch_bounds__(256) void ln_kernel(
    const float* __restrict__ xr, const float* __restrict__ y,
    const float* __restrict__ g, const float* __restrict__ beta,
    float* __restrict__ of, __bf16* __restrict__ oh)
{
    __shared__ float red[2][4];
    const int row = blockIdx.x, t = threadIdx.x;
    const int lane = t & 63, wave = t >> 6;
    const int idx = row * 256 + t;
    float4 a = ((const float4*)xr)[idx];
    float4 c = ((const float4*)y)[idx];
    float4 v;
    v.x = a.x + c.x; v.y = a.y + c.y; v.z = a.z + c.z; v.w = a.w + c.w;
    float s1 = v.x + v.y + v.z + v.w;
    float s2 = v.x * v.x + v.y * v.y + v.z * v.z + v.w * v.w;
    #pragma unroll
    for (int off = 1; off < 64; off <<= 1) {
        s1 += __shfl_xor(s1, off);
        s2 += __shfl_xor(s2, off);
    }
    if (lane == 0) { red[0][wave] = s1; red[1][wave] = s2; }
    __syncthreads();
    s1 = red[0][0] + red[0][1] + red[0][2] + red[0][3];
    s2 = red[1][0] + red[1][1] + red[1][2] + red[1][3];
    const float mu   = s1 * (1.f / Hc);
    const float var  = s2 * (1.f / Hc) - mu * mu;
    const float rstd = rsqrtf(var + EPSc);
    float4 gg = ((const float4*)g)[t];
    float4 bb = ((const float4*)beta)[t];
    float4 r;
    r.x = (v.x - mu) * rstd * gg.x + bb.x;
    r.y = (v.y - mu) * rstd * gg.y + bb.y;
    r.z = (v.z - mu) * rstd * gg.z + bb.z;
    r.w = (v.w - mu) * rstd * gg.w + bb.w;
    ((float4*)of)[idx] = r;
    bf16x4 hh = { (__bf16)r.x, (__bf16)r.y, (__bf16)r.z, (__bf16)r.w };
    ((bf16x4*)oh)[idx] = hh;
}

// ---------------------------------------------------------------------------
extern "C" void kernel_launch(void* const* d_in, const int* in_sizes, int n_in,
                              void* d_out, int out_size, void* d_ws, size_t ws_size,
                              hipStream_t stream)
{
    const float* inp = (const float*)d_in[0];
    const float* pos = (const float*)d_in[1];
    const float* Wq  = (const float*)d_in[2];
    const float* bq  = (const float*)d_in[3];
    const float* Wk  = (const float*)d_in[4];
    const float* bk  = (const float*)d_in[5];
    const float* Wv  = (const float*)d_in[6];
    const float* bv  = (const float*)d_in[7];
    const float* Wo  = (const float*)d_in[8];
    const float* bo  = (const float*)d_in[9];
    const float* lng = (const float*)d_in[10];
    const float* lnb = (const float*)d_in[11];
    const float* W1  = (const float*)d_in[12];
    const float* b1  = (const float*)d_in[13];
    const float* W2  = (const float*)d_in[14];
    const float* b2  = (const float*)d_in[15];

    char* ws = (char*)d_ws;
    const size_t MB = 1u << 20;
    float*  src_f = (float*)(ws);              // 16 MB
    __bf16* src_h = (__bf16*)(ws + 16 * MB);   //  8 MB
    __bf16* src_l = (__bf16*)(ws + 24 * MB);   //  8 MB
    __bf16* qh    = (__bf16*)(ws + 32 * MB);   //  8 MB (head-major)
    __bf16* kh    = (__bf16*)(ws + 40 * MB);   //  8 MB
    __bf16* vv    = (__bf16*)(ws + 48 * MB);   //  8 MB
    __bf16* ctx   = (__bf16*)(ws + 56 * MB);   //  8 MB (row-major)
    __bf16* ql    = (__bf16*)(ws + 64 * MB);   //  8 MB (layer 0 only)
    __bf16* kl    = (__bf16*)(ws + 72 * MB);   //  8 MB
    float*  tmp   = (float*)(ws + 80 * MB);    // 16 MB
    __bf16* h1    = (__bf16*)(ws + 32 * MB);   // 32 MB alias (qh..ctx, dead by FFN)
    __bf16* wqT   = (__bf16*)(ws + 96 * MB);   // 12 MB each
    __bf16* wkT   = (__bf16*)(ws + 108 * MB);
    __bf16* wvT   = (__bf16*)(ws + 120 * MB);
    __bf16* woT   = (__bf16*)(ws + 132 * MB);
    __bf16* w1T   = (__bf16*)(ws + 144 * MB);  // 48 MB
    __bf16* w2T   = (__bf16*)(ws + 192 * MB);  // 48 MB ; total 240 MB

    const int M = Bc * Sc;  // 4096

    // one-time weight transpose + bf16 convert
    wconv_kernel<<<dim3(16, 16, 6), 256, 0, stream>>>(Wq, wqT, Hc, Hc);
    wconv_kernel<<<dim3(16, 16, 6), 256, 0, stream>>>(Wk, wkT, Hc, Hc);
    wconv_kernel<<<dim3(16, 16, 6), 256, 0, stream>>>(Wv, wvT, Hc, Hc);
    wconv_kernel<<<dim3(16, 16, 6), 256, 0, stream>>>(Wo, woT, Hc, Hc);
    wconv_kernel<<<dim3(64, 16, 6), 256, 0, stream>>>(W1, w1T, Hc, PFc);
    wconv_kernel<<<dim3(16, 64, 6), 256, 0, stream>>>(W2, w2T, PFc, Hc);

    embed_kernel<<<2048, 256, 0, stream>>>(inp, pos, src_f, src_h, src_l);

    for (int l = 0; l < Lc; ++l) {
        const size_t wHH = (size_t)l * Hc * Hc;
        const size_t wH  = (size_t)l * Hc;
        if (l == 0) {
            QKVArgs qa = { Wq, Wk, Wv, bq, bk, bv, qh, ql, kh, kl, vv };
            qkv0_kernel<<<dim3(24, 32), 256, 0, stream>>>(src_h, src_l, qa);
            attn_kernel<1><<<dim3(32, 16, 2), 256, 0, stream>>>(qh, ql, kh, kl, vv, ctx);
        } else {
            QKVBT qa = { wqT + wHH, wkT + wHH, wvT + wHH, bq + wH, bk + wH, bv + wH,
                         qh, kh, vv };
            qkv_bt_kernel<<<dim3(24, 32), 256, 0, stream>>>(src_h, qa);
            attn_kernel<0><<<dim3(32, 16, 2), 256, 0, stream>>>(qh, nullptr, kh, nullptr, vv, ctx);
        }
        gemm_bt_kernel<64, 0, false><<<dim3(8, 64), 256, 0, stream>>>(
            ctx, woT + wHH, bo + wH, tmp, M, Hc, Hc);
        ln_kernel<<<M, 256, 0, stream>>>(src_f, tmp, lng + wH, lnb + wH, src_f, src_h);
        gemm_bt_kernel<128, 1, true><<<dim3(32, 32), 256, 0, stream>>>(
            src_h, w1T + (size_t)l * Hc * PFc, b1 + (size_t)l * PFc, h1, M, PFc, Hc);
        gemm_bt_kernel<64, 0, false><<<dim3(8, 64), 256, 0, stream>>>(
            h1, w2T + (size_t)l * PFc * Hc, b2 + wH, tmp, M, Hc, PFc);
        float* dst = (l == Lc - 1) ? (float*)d_out : src_f;
        ln_kernel<<<M, 256, 0, stream>>>(src_f, tmp, lng + wH, lnb + wH, dst, src_h);
    }
}

// Round 6
// 1929.076 us; speedup vs baseline: 2.7615x; 1.0681x over previous
//
#include <hip/hip_runtime.h>
#include <cstdint>

constexpr int Bc = 2, Sc = 2048, Hc = 1024, NHc = 16, HDc = 64, PFc = 4096, Lc = 6;
constexpr float EPSc = 1e-5f;

using f32x4  = __attribute__((ext_vector_type(4))) float;
using bf16x8 = __attribute__((ext_vector_type(8))) __bf16;
using bf16x4 = __attribute__((ext_vector_type(4))) __bf16;
using u32x4  = __attribute__((ext_vector_type(4))) unsigned;

__device__ __forceinline__ f32x4 mfma16(bf16x8 a, bf16x8 b, f32x4 c) {
    return __builtin_amdgcn_mfma_f32_16x16x32_bf16(a, b, c, 0, 0, 0);
}

__device__ __forceinline__ void gload_lds16(const void* g, void* l) {
    __builtin_amdgcn_global_load_lds(
        (__attribute__((address_space(1))) void*)(uintptr_t)g,
        (__attribute__((address_space(3))) void*)(uint32_t)(uintptr_t)l,
        16, 0, 0);
}

struct HL { __bf16 h, l; };
__device__ __forceinline__ HL split2(float v) {
    HL r;
    r.h = (__bf16)v;
    r.l = (__bf16)(v - (float)r.h);
    return r;
}

__device__ __forceinline__ unsigned bfbits(__bf16 x) {
    return (unsigned)__builtin_bit_cast(unsigned short, x);
}
__device__ __forceinline__ unsigned packbf(float a, float b) {
    return bfbits((__bf16)a) | (bfbits((__bf16)b) << 16);
}

// ---------------------------------------------------------------------------
// Weight convert: f32 [K][N] -> bf16 [N][K], 64x64 tiles via LDS.
// ---------------------------------------------------------------------------
__global__ __launch_bounds__(256) void wconv_kernel(
    const float* __restrict__ in, __bf16* __restrict__ out, int K, int N)
{
    __shared__ float tile[64][65];
    const int t = threadIdx.x;
    const size_t lstride = (size_t)K * N;
    const float* ip = in + (size_t)blockIdx.z * lstride;
    __bf16* op = out + (size_t)blockIdx.z * lstride;
    const int n0 = blockIdx.x * 64, k0 = blockIdx.y * 64;
    #pragma unroll
    for (int c = 0; c < 4; ++c) {
        int idx = c * 256 + t;
        int row = idx >> 4;
        int c4  = idx & 15;
        float4 v = *(const float4*)(ip + (size_t)(k0 + row) * N + n0 + c4 * 4);
        tile[row][c4 * 4 + 0] = v.x; tile[row][c4 * 4 + 1] = v.y;
        tile[row][c4 * 4 + 2] = v.z; tile[row][c4 * 4 + 3] = v.w;
    }
    __syncthreads();
    #pragma unroll
    for (int c = 0; c < 4; ++c) {
        int idx = c * 256 + t;
        int n  = idx >> 4;
        int k4 = idx & 15;
        bf16x4 hh = { (__bf16)tile[k4 * 4 + 0][n], (__bf16)tile[k4 * 4 + 1][n],
                      (__bf16)tile[k4 * 4 + 2][n], (__bf16)tile[k4 * 4 + 3][n] };
        *(bf16x4*)(op + (size_t)(n0 + n) * K + k0 + k4 * 4) = hh;
    }
}

// ---------------------------------------------------------------------------
// Embed: src = in*32 + pos ; f32 master + split bf16
// ---------------------------------------------------------------------------
__global__ __launch_bounds__(256) void embed_kernel(
    const float* __restrict__ in, const float* __restrict__ pos,
    float* __restrict__ sf, __bf16* __restrict__ sh, __bf16* __restrict__ sl)
{
    const int n4 = (Bc * Sc * Hc) / 4;
    const int pmask = (Sc * Hc / 4) - 1;
    for (int i = blockIdx.x * 256 + threadIdx.x; i < n4; i += gridDim.x * 256) {
        float4 a = ((const float4*)in)[i];
        float4 p = ((const float4*)pos)[i & pmask];
        float4 r;
        r.x = a.x * 32.f + p.x; r.y = a.y * 32.f + p.y;
        r.z = a.z * 32.f + p.z; r.w = a.w * 32.f + p.w;
        ((float4*)sf)[i] = r;
        HL e0 = split2(r.x), e1 = split2(r.y), e2 = split2(r.z), e3 = split2(r.w);
        bf16x4 hh = { e0.h, e1.h, e2.h, e3.h };
        bf16x4 ll = { e0.l, e1.l, e2.l, e3.l };
        ((bf16x4*)sh)[i] = hh;
        ((bf16x4*)sl)[i] = ll;
    }
}

// ---------------------------------------------------------------------------
// GEMM on pre-transposed bf16 weights. BM x 128 tile, BK=64, 4 waves.
// ---------------------------------------------------------------------------
template<int BM, int OUTMODE, bool RELU>
__global__ __launch_bounds__(256) void gemm_bt_kernel(
    const __bf16* __restrict__ A, const __bf16* __restrict__ Wt,
    const float* __restrict__ bias, void* __restrict__ out,
    int M, int N, int K)
{
    constexpr int MI = BM / 32;
    __shared__ alignas(16) __bf16 Alds[BM * 64];
    __shared__ alignas(16) __bf16 Blds[128 * 64];

    const int tid = threadIdx.x, lane = tid & 63, wave = tid >> 6;
    const int lr = lane & 15, lg = lane >> 4;
    const int m0 = blockIdx.y * BM, n0 = blockIdx.x * 128;
    const int wm = (wave >> 1) * (BM / 2), wn = (wave & 1) * 64;

    f32x4 acc[MI][4] = {};

    for (int k0 = 0; k0 < K; k0 += 64) {
        #pragma unroll
        for (int c = 0; c < BM / 32; ++c) {
            int li = c * 256 + tid;
            int row = li >> 3;
            int lcb = ((li & 7) << 4) ^ ((row & 7) << 4);
            gload_lds16(A + (size_t)(m0 + row) * K + k0 + (lcb >> 1),
                        (char*)Alds + (size_t)(c * 256 + wave * 64) * 16);
        }
        #pragma unroll
        for (int c = 0; c < 4; ++c) {
            int li = c * 256 + tid;
            int row = li >> 3;
            int lcb = ((li & 7) << 4) ^ ((row & 7) << 4);
            gload_lds16(Wt + (size_t)(n0 + row) * K + k0 + (lcb >> 1),
                        (char*)Blds + (size_t)(c * 256 + wave * 64) * 16);
        }
        __syncthreads();

        bf16x8 af[2][MI], bfr[2][4];
        #pragma unroll
        for (int ks = 0; ks < 2; ++ks) {
            #pragma unroll
            for (int i = 0; i < MI; ++i) {
                int ra = wm + i * 16 + lr;
                int pa = (ks * 64 + lg * 16) ^ ((ra & 7) << 4);
                af[ks][i] = *(const bf16x8*)((const char*)Alds + ra * 128 + pa);
            }
            #pragma unroll
            for (int i = 0; i < 4; ++i) {
                int rb = wn + i * 16 + lr;
                int pb = (ks * 64 + lg * 16) ^ ((rb & 7) << 4);
                bfr[ks][i] = *(const bf16x8*)((const char*)Blds + rb * 128 + pb);
            }
        }
        #pragma unroll
        for (int ks = 0; ks < 2; ++ks)
            #pragma unroll
            for (int mi = 0; mi < MI; ++mi)
                #pragma unroll
                for (int ni = 0; ni < 4; ++ni)
                    acc[mi][ni] = mfma16(af[ks][mi], bfr[ks][ni], acc[mi][ni]);
        __syncthreads();
    }

    #pragma unroll
    for (int ni = 0; ni < 4; ++ni) {
        int col = n0 + wn + ni * 16 + lr;
        float bv = bias[col];
        #pragma unroll
        for (int mi = 0; mi < MI; ++mi) {
            int rowb = m0 + wm + mi * 16 + lg * 4;
            #pragma unroll
            for (int r = 0; r < 4; ++r) {
                float v = acc[mi][ni][r] + bv;
                if (RELU) v = fmaxf(v, 0.f);
                size_t idx = (size_t)(rowb + r) * N + col;
                if constexpr (OUTMODE == 0) ((float*)out)[idx] = v;
                else                        ((__bf16*)out)[idx] = (__bf16)v;
            }
        }
    }
}

// ---------------------------------------------------------------------------
// Fused QKV on pre-transposed bf16 weights (layers >= 1). Head-major out.
// ---------------------------------------------------------------------------
struct QKVBT {
    const __bf16 *wq, *wk, *wv;
    const float *bq, *bk, *bv;
    __bf16 *q, *k, *v;
};

__global__ __launch_bounds__(256) void qkv_bt_kernel(
    const __bf16* __restrict__ A, QKVBT a)
{
    constexpr int N = Hc, K = Hc;
    __shared__ alignas(16) __bf16 Alds[128 * 64];
    __shared__ alignas(16) __bf16 Blds[128 * 64];

    const int tid = threadIdx.x, lane = tid & 63, wave = tid >> 6;
    const int lr = lane & 15, lg = lane >> 4;
    const int gx = blockIdx.x;
    const int widx = gx >> 3;
    const int n0 = (gx & 7) * 128;
    const int m0 = blockIdx.y * 128;
    const int wm = (wave >> 1) * 64, wn = (wave & 1) * 64;

    const __bf16* Wt  = (widx == 0) ? a.wq : (widx == 1) ? a.wk : a.wv;
    const float* bias = (widx == 0) ? a.bq : (widx == 1) ? a.bk : a.bv;

    f32x4 acc[4][4] = {};

    for (int k0 = 0; k0 < K; k0 += 64) {
        #pragma unroll
        for (int c = 0; c < 4; ++c) {
            int li = c * 256 + tid;
            int row = li >> 3;
            int lcb = ((li & 7) << 4) ^ ((row & 7) << 4);
            gload_lds16(A + (size_t)(m0 + row) * K + k0 + (lcb >> 1),
                        (char*)Alds + (size_t)(c * 256 + wave * 64) * 16);
            gload_lds16(Wt + (size_t)(n0 + row) * K + k0 + (lcb >> 1),
                        (char*)Blds + (size_t)(c * 256 + wave * 64) * 16);
        }
        __syncthreads();

        bf16x8 af[2][4], bfr[2][4];
        #pragma unroll
        for (int ks = 0; ks < 2; ++ks) {
            #pragma unroll
            for (int i = 0; i < 4; ++i) {
                int ra = wm + i * 16 + lr;
                int pa = (ks * 64 + lg * 16) ^ ((ra & 7) << 4);
                af[ks][i] = *(const bf16x8*)((const char*)Alds + ra * 128 + pa);
                int rb = wn + i * 16 + lr;
                int pb = (ks * 64 + lg * 16) ^ ((rb & 7) << 4);
                bfr[ks][i] = *(const bf16x8*)((const char*)Blds + rb * 128 + pb);
            }
        }
        #pragma unroll
        for (int ks = 0; ks < 2; ++ks)
            #pragma unroll
            for (int mi = 0; mi < 4; ++mi)
                #pragma unroll
                for (int ni = 0; ni < 4; ++ni)
                    acc[mi][ni] = mfma16(af[ks][mi], bfr[ks][ni], acc[mi][ni]);
        __syncthreads();
    }

    __bf16* outp = (widx == 0) ? a.q : (widx == 1) ? a.k : a.v;
    #pragma unroll
    for (int ni = 0; ni < 4; ++ni) {
        int col = n0 + wn + ni * 16 + lr;
        float bv = bias[col];
        int hh = col >> 6, d = col & 63;
        #pragma unroll
        for (int mi = 0; mi < 4; ++mi) {
            int rowb = m0 + wm + mi * 16 + lg * 4;
            #pragma unroll
            for (int r = 0; r < 4; ++r) {
                int row = rowb + r;
                int bb = row >> 11, s = row & (Sc - 1);
                outp[((size_t)(bb * NHc + hh) * Sc + s) * HDc + d] =
                    (__bf16)(acc[mi][ni][r] + bv);
            }
        }
    }
}

// ---------------------------------------------------------------------------
// Layer-0 QKV (full split precision, f32 weights). Head-major out, q/k hi+lo.
// ---------------------------------------------------------------------------
struct QKVArgs {
    const float *Wq, *Wk, *Wv, *bq, *bk, *bv;
    __bf16 *qh, *ql, *kh, *kl, *vv;
};

__global__ __launch_bounds__(256) void qkv0_kernel(
    const __bf16* __restrict__ Ahi, const __bf16* __restrict__ Alo, QKVArgs a)
{
    constexpr int N = Hc, K = Hc;
    __shared__ alignas(16) __bf16 AldsH[128 * 64];
    __shared__ alignas(16) __bf16 AldsL[128 * 64];
    __shared__ alignas(16) __bf16 BldsH[128 * 64];
    __shared__ alignas(16) __bf16 BldsL[128 * 64];

    const int tid  = threadIdx.x;
    const int lane = tid & 63;
    const int wave = tid >> 6;
    const int lr   = lane & 15;
    const int lg   = lane >> 4;
    const int gx   = blockIdx.x;
    const int widx = gx >> 3;
    const int n0   = (gx & 7) * 128;
    const int m0   = blockIdx.y * 128;
    const int wm   = (wave >> 1) * 64;
    const int wn   = (wave & 1) * 64;
    const int bn   = tid & 127;
    const int bkh  = (tid >> 7) * 32;

    const float* Bw   = (widx == 0) ? a.Wq : (widx == 1) ? a.Wk : a.Wv;
    const float* bias = (widx == 0) ? a.bq : (widx == 1) ? a.bk : a.bv;

    f32x4 acc[4][4] = {};
    const float* bsrc0 = Bw + (size_t)bkh * N + n0 + bn;

    for (int k0 = 0; k0 < K; k0 += 64) {
        #pragma unroll
        for (int c = 0; c < 4; ++c) {
            int li  = c * 256 + tid;
            int row = li >> 3;
            int lcb = ((li & 7) << 4) ^ ((row & 7) << 4);
            size_t goff = (size_t)(m0 + row) * K + k0 + (lcb >> 1);
            size_t loff = (size_t)(c * 256 + wave * 64) * 16;
            gload_lds16(Ahi + goff, (char*)AldsH + loff);
            gload_lds16(Alo + goff, (char*)AldsL + loff);
        }
        const float* bs = bsrc0 + (size_t)k0 * N;
        #pragma unroll
        for (int c = 0; c < 4; ++c) {
            bf16x8 ph, plv;
            #pragma unroll
            for (int j = 0; j < 8; ++j) {
                HL e = split2(bs[(size_t)(c * 8 + j) * N]);
                ph[j] = e.h;
                plv[j] = e.l;
            }
            int pcb = (bkh * 2 + c * 16) ^ ((bn & 7) << 4);
            *(bf16x8*)((char*)BldsH + bn * 128 + pcb) = ph;
            *(bf16x8*)((char*)BldsL + bn * 128 + pcb) = plv;
        }
        __syncthreads();

        bf16x8 ah[2][4], al[2][4], bh[2][4], bl[2][4];
        #pragma unroll
        for (int ks = 0; ks < 2; ++ks) {
            #pragma unroll
            for (int i = 0; i < 4; ++i) {
                int ra = wm + i * 16 + lr;
                int pa = (ks * 64 + lg * 16) ^ ((ra & 7) << 4);
                ah[ks][i] = *(const bf16x8*)((const char*)AldsH + ra * 128 + pa);
                al[ks][i] = *(const bf16x8*)((const char*)AldsL + ra * 128 + pa);
                int rb = wn + i * 16 + lr;
                int pb = (ks * 64 + lg * 16) ^ ((rb & 7) << 4);
                bh[ks][i] = *(const bf16x8*)((const char*)BldsH + rb * 128 + pb);
                bl[ks][i] = *(const bf16x8*)((const char*)BldsL + rb * 128 + pb);
            }
        }
        #pragma unroll
        for (int ks = 0; ks < 2; ++ks)
            #pragma unroll
            for (int mi = 0; mi < 4; ++mi)
                #pragma unroll
                for (int ni = 0; ni < 4; ++ni) {
                    acc[mi][ni] = mfma16(ah[ks][mi], bh[ks][ni], acc[mi][ni]);
                    acc[mi][ni] = mfma16(al[ks][mi], bh[ks][ni], acc[mi][ni]);
                    acc[mi][ni] = mfma16(ah[ks][mi], bl[ks][ni], acc[mi][ni]);
                }
        __syncthreads();
    }

    __bf16* outh = (widx == 0) ? a.qh : (widx == 1) ? a.kh : a.vv;
    __bf16* outl = (widx == 0) ? a.ql : a.kl;
    #pragma unroll
    for (int ni = 0; ni < 4; ++ni) {
        int col = n0 + wn + ni * 16 + lr;
        float bv = bias[col];
        int hh = col >> 6, d = col & 63;
        #pragma unroll
        for (int mi = 0; mi < 4; ++mi) {
            int rowb = m0 + wm + mi * 16 + lg * 4;
            #pragma unroll
            for (int r = 0; r < 4; ++r) {
                int row = rowb + r;
                int bb = row >> 11, s = row & (Sc - 1);
                size_t idx = ((size_t)(bb * NHc + hh) * Sc + s) * HDc + d;
                float v = acc[mi][ni][r] + bv;
                if (widx < 2) {
                    HL e = split2(v);
                    outh[idx] = e.h;
                    outl[idx] = e.l;
                } else {
                    outh[idx] = (__bf16)v;
                }
            }
        }
    }
}

// ---------------------------------------------------------------------------
// Flash attention, v2. Key-slot permutation makes PV A-operand lane-local
// (no P LDS round-trip). V staged permuted+transposed in LDS with packed b32
// conflict-free writes. K/VT double-buffered; next-tile loads issued before
// compute (T14). One barrier per iter.
// Slot map: key[kg1 kg0 lg1 lg0 r1 r0] -> slot[kg1 lg1 lg0 kg0 r1 r0].
// ---------------------------------------------------------------------------
template<int QKSPLIT>
__global__ __launch_bounds__(256) void attn_kernel(
    const __bf16* __restrict__ Qh, const __bf16* __restrict__ Ql,
    const __bf16* __restrict__ Kh, const __bf16* __restrict__ Kl,
    const __bf16* __restrict__ V, __bf16* __restrict__ O)
{
    __shared__ alignas(16) __bf16 Ksh[2][64 * 64];
    __shared__ alignas(16) __bf16 Klo[QKSPLIT ? 2 : 1][QKSPLIT ? 64 * 64 : 8];
    __shared__ alignas(16) __bf16 VT[2][64 * 64];

    const int tid = threadIdx.x;
    const int lane = tid & 63, wave = tid >> 6;
    const int lr = lane & 15, lg = lane >> 4;
    const int h = blockIdx.y, b = blockIdx.z;
    const int q0 = blockIdx.x * 64 + wave * 16;

    const size_t headoff = ((size_t)b * NHc + h) * Sc * HDc;
    const __bf16* Qb  = Qh + headoff;
    const __bf16* Kb  = Kh + headoff;
    const __bf16* Klb = QKSPLIT ? (Kl + headoff) : nullptr;
    const __bf16* Vb  = V + headoff;

    const size_t qrow = (size_t)(q0 + lr) * HDc;
    bf16x8 qf0 = *(const bf16x8*)(Qb + qrow + lg * 8);
    bf16x8 qf1 = *(const bf16x8*)(Qb + qrow + 32 + lg * 8);
    bf16x8 qlo0, qlo1;
    if constexpr (QKSPLIT) {
        const __bf16* Qlb = Ql + headoff;
        qlo0 = *(const bf16x8*)(Qlb + qrow + lg * 8);
        qlo1 = *(const bf16x8*)(Qlb + qrow + 32 + lg * 8);
    }

    // V staging map: thread owns key-pair kp (keys 2kp,2kp+1), d in [dblk*8, +8)
    const int kp = tid & 31, dblk = tid >> 5;
    const int sp = (kp & 0x11) | ((kp & 0x06) << 1) | ((kp & 0x08) >> 2);

    auto stageK = [&](int kt, int buf) {
        #pragma unroll
        for (int c = 0; c < 2; ++c) {
            int li  = c * 256 + tid;
            int row = li >> 3;
            int lcb = ((li & 7) << 4) ^ ((row & 7) << 4);
            size_t goff = (size_t)(kt * 64 + row) * HDc + (lcb >> 1);
            size_t loff = (size_t)(c * 256 + wave * 64) * 16;
            gload_lds16(Kb + goff, (char*)Ksh[buf] + loff);
            if constexpr (QKSPLIT)
                gload_lds16(Klb + goff, (char*)Klo[buf] + loff);
        }
    };
    auto loadV = [&](int kt, bf16x8& va, bf16x8& vb2) {
        const __bf16* vs = Vb + (size_t)(kt * 64 + 2 * kp) * HDc + dblk * 8;
        va  = *(const bf16x8*)vs;
        vb2 = *(const bf16x8*)(vs + HDc);
    };
    auto writeVT = [&](int buf, bf16x8 va, bf16x8 vb2) {
        #pragma unroll
        for (int j = 0; j < 8; ++j) {
            int d = dblk * 8 + j;
            unsigned u = bfbits(va[j]) | (bfbits(vb2[j]) << 16);
            int byte = d * 128 + ((sp * 4) ^ ((d & 7) << 4));
            *(unsigned*)((char*)VT[buf] + byte) = u;
        }
    };

    f32x4 o[4] = {};
    float m = -1e30f, lsum = 0.f;

    // prologue: stage tile 0
    stageK(0, 0);
    {
        bf16x8 va, vb2;
        loadV(0, va, vb2);
        writeVT(0, va, vb2);
    }
    __syncthreads();

    int cur = 0;
    for (int kt = 0; kt < Sc / 64; ++kt) {
        const int nb = cur ^ 1;
        const bool pf = (kt + 1 < Sc / 64);
        bf16x8 va, vb2;
        if (pf) {
            stageK(kt + 1, nb);          // async into other buffer
            loadV(kt + 1, va, vb2);      // global->reg, hidden under compute
        }

        // ---- QK^T from Ksh[cur] ----
        const char* Kc = (const char*)Ksh[cur];
        const char* Klc = (const char*)Klo[QKSPLIT ? cur : 0];
        f32x4 s[4];
        #pragma unroll
        for (int kg = 0; kg < 4; ++kg) {
            int ra = kg * 16 + lr;
            int pa0 = (lg * 16) ^ ((ra & 7) << 4);
            int pa1 = (64 + lg * 16) ^ ((ra & 7) << 4);
            bf16x8 kf0 = *(const bf16x8*)(Kc + ra * 128 + pa0);
            bf16x8 kf1 = *(const bf16x8*)(Kc + ra * 128 + pa1);
            f32x4 t = {};
            t = mfma16(kf0, qf0, t);
            t = mfma16(kf1, qf1, t);
            if constexpr (QKSPLIT) {
                bf16x8 kg0 = *(const bf16x8*)(Klc + ra * 128 + pa0);
                bf16x8 kg1 = *(const bf16x8*)(Klc + ra * 128 + pa1);
                t = mfma16(kg0, qf0, t);
                t = mfma16(kg1, qf1, t);
                t = mfma16(kf0, qlo0, t);
                t = mfma16(kf1, qlo1, t);
            }
            s[kg] = t;
        }

        // ---- online softmax (q-row = lr; keys spread over kg,r) ----
        float mt = -1e30f;
        #pragma unroll
        for (int kg = 0; kg < 4; ++kg)
            #pragma unroll
            for (int r = 0; r < 4; ++r) {
                s[kg][r] *= 0.125f;
                mt = fmaxf(mt, s[kg][r]);
            }
        mt = fmaxf(mt, __shfl_xor(mt, 16));
        mt = fmaxf(mt, __shfl_xor(mt, 32));
        if (!__all(mt <= m)) {           // skip is exact: fac==1 for all rows
            float mnew = fmaxf(m, mt);
            float fac = __expf(m - mnew);
            m = mnew;
            lsum *= fac;
            #pragma unroll
            for (int r = 0; r < 4; ++r) {
                float fr = __shfl(fac, (lg << 4) | (lg * 4 + r));
                #pragma unroll
                for (int nd = 0; nd < 4; ++nd) o[nd][r] *= fr;
            }
        }
        float ps = 0.f;
        #pragma unroll
        for (int kg = 0; kg < 4; ++kg)
            #pragma unroll
            for (int r = 0; r < 4; ++r) {
                float p = __expf(s[kg][r] - m);
                ps += p;
                s[kg][r] = p;
            }
        ps += __shfl_xor(ps, 16);
        ps += __shfl_xor(ps, 32);
        lsum += ps;

        // ---- PV: A-operand lane-local via slot permutation ----
        #pragma unroll
        for (int kh2 = 0; kh2 < 2; ++kh2) {
            u32x4 pk;
            pk[0] = packbf(s[2 * kh2][0],     s[2 * kh2][1]);
            pk[1] = packbf(s[2 * kh2][2],     s[2 * kh2][3]);
            pk[2] = packbf(s[2 * kh2 + 1][0], s[2 * kh2 + 1][1]);
            pk[3] = packbf(s[2 * kh2 + 1][2], s[2 * kh2 + 1][3]);
            bf16x8 paf = __builtin_bit_cast(bf16x8, pk);
            #pragma unroll
            for (int nd = 0; nd < 4; ++nd) {
                int d = nd * 16 + lr;
                int byte = d * 128 + ((64 * kh2 + 16 * lg) ^ ((d & 7) << 4));
                bf16x8 vbf = *(const bf16x8*)((const char*)VT[cur] + byte);
                o[nd] = mfma16(paf, vbf, o[nd]);
            }
        }

        if (pf) writeVT(nb, va, vb2);    // vmcnt wait on V regs here
        __syncthreads();                 // drains K gload(kt+1) too (hidden)
        cur = nb;
    }

    // ---- epilogue: row-major ctx [B,S,H] ----
    #pragma unroll
    for (int r = 0; r < 4; ++r) {
        float lv  = __shfl(lsum, (lg << 4) | (lg * 4 + r));
        float inv = 1.f / lv;
        size_t orow = ((size_t)b * Sc + q0 + lg * 4 + r) * Hc + h * HDc;
        #pragma unroll
        for (int nd = 0; nd < 4; ++nd)
            O[orow + nd * 16 + lr] = (__bf16)(o[nd][r] * inv);
    }
}

// ---------------------------------------------------------------------------
// Fused residual + LayerNorm: f32 master + bf16 copy
// ---------------------------------------------------------------------------
__global__ __launch_bounds__(256) void ln_kernel(
    const float* __restrict__ xr, const float* __restrict__ y,
    const float* __restrict__ g, const float* __restrict__ beta,
    float* __restrict__ of, __bf16* __restrict__ oh)
{
    __shared__ float red[2][4];
    const int row = blockIdx.x, t = threadIdx.x;
    const int lane = t & 63, wave = t >> 6;
    const int idx = row * 256 + t;
    float4 a = ((const float4*)xr)[idx];
    float4 c = ((const float4*)y)[idx];
    float4 v;
    v.x = a.x + c.x; v.y = a.y + c.y; v.z = a.z + c.z; v.w = a.w + c.w;
    float s1 = v.x + v.y + v.z + v.w;
    float s2 = v.x * v.x + v.y * v.y + v.z * v.z + v.w * v.w;
    #pragma unroll
    for (int off = 1; off < 64; off <<= 1) {
        s1 += __shfl_xor(s1, off);
        s2 += __shfl_xor(s2, off);
    }
    if (lane == 0) { red[0][wave] = s1; red[1][wave] = s2; }
    __syncthreads();
    s1 = red[0][0] + red[0][1] + red[0][2] + red[0][3];
    s2 = red[1][0] + red[1][1] + red[1][2] + red[1][3];
    const float mu   = s1 * (1.f / Hc);
    const float var  = s2 * (1.f / Hc) - mu * mu;
    const float rstd = rsqrtf(var + EPSc);
    float4 gg = ((const float4*)g)[t];
    float4 bb = ((const float4*)beta)[t];
    float4 r;
    r.x = (v.x - mu) * rstd * gg.x + bb.x;
    r.y = (v.y - mu) * rstd * gg.y + bb.y;
    r.z = (v.z - mu) * rstd * gg.z + bb.z;
    r.w = (v.w - mu) * rstd * gg.w + bb.w;
    ((float4*)of)[idx] = r;
    bf16x4 hh = { (__bf16)r.x, (__bf16)r.y, (__bf16)r.z, (__bf16)r.w };
    ((bf16x4*)oh)[idx] = hh;
}

// ---------------------------------------------------------------------------
extern "C" void kernel_launch(void* const* d_in, const int* in_sizes, int n_in,
                              void* d_out, int out_size, void* d_ws, size_t ws_size,
                              hipStream_t stream)
{
    const float* inp = (const float*)d_in[0];
    const float* pos = (const float*)d_in[1];
    const float* Wq  = (const float*)d_in[2];
    const float* bq  = (const float*)d_in[3];
    const float* Wk  = (const float*)d_in[4];
    const float* bk  = (const float*)d_in[5];
    const float* Wv  = (const float*)d_in[6];
    const float* bv  = (const float*)d_in[7];
    const float* Wo  = (const float*)d_in[8];
    const float* bo  = (const float*)d_in[9];
    const float* lng = (const float*)d_in[10];
    const float* lnb = (const float*)d_in[11];
    const float* W1  = (const float*)d_in[12];
    const float* b1  = (const float*)d_in[13];
    const float* W2  = (const float*)d_in[14];
    const float* b2  = (const float*)d_in[15];

    char* ws = (char*)d_ws;
    const size_t MB = 1u << 20;
    float*  src_f = (float*)(ws);              // 16 MB
    __bf16* src_h = (__bf16*)(ws + 16 * MB);   //  8 MB
    __bf16* src_l = (__bf16*)(ws + 24 * MB);   //  8 MB
    __bf16* qh    = (__bf16*)(ws + 32 * MB);   //  8 MB (head-major)
    __bf16* kh    = (__bf16*)(ws + 40 * MB);   //  8 MB
    __bf16* vv    = (__bf16*)(ws + 48 * MB);   //  8 MB
    __bf16* ctx   = (__bf16*)(ws + 56 * MB);   //  8 MB (row-major)
    __bf16* ql    = (__bf16*)(ws + 64 * MB);   //  8 MB (layer 0 only)
    __bf16* kl    = (__bf16*)(ws + 72 * MB);   //  8 MB
    float*  tmp   = (float*)(ws + 80 * MB);    // 16 MB
    __bf16* h1    = (__bf16*)(ws + 32 * MB);   // 32 MB alias (qh..ctx, dead by FFN)
    __bf16* wqT   = (__bf16*)(ws + 96 * MB);   // 12 MB each
    __bf16* wkT   = (__bf16*)(ws + 108 * MB);
    __bf16* wvT   = (__bf16*)(ws + 120 * MB);
    __bf16* woT   = (__bf16*)(ws + 132 * MB);
    __bf16* w1T   = (__bf16*)(ws + 144 * MB);  // 48 MB
    __bf16* w2T   = (__bf16*)(ws + 192 * MB);  // 48 MB ; total 240 MB

    const int M = Bc * Sc;  // 4096

    wconv_kernel<<<dim3(16, 16, 6), 256, 0, stream>>>(Wq, wqT, Hc, Hc);
    wconv_kernel<<<dim3(16, 16, 6), 256, 0, stream>>>(Wk, wkT, Hc, Hc);
    wconv_kernel<<<dim3(16, 16, 6), 256, 0, stream>>>(Wv, wvT, Hc, Hc);
    wconv_kernel<<<dim3(16, 16, 6), 256, 0, stream>>>(Wo, woT, Hc, Hc);
    wconv_kernel<<<dim3(64, 16, 6), 256, 0, stream>>>(W1, w1T, Hc, PFc);
    wconv_kernel<<<dim3(16, 64, 6), 256, 0, stream>>>(W2, w2T, PFc, Hc);

    embed_kernel<<<2048, 256, 0, stream>>>(inp, pos, src_f, src_h, src_l);

    for (int l = 0; l < Lc; ++l) {
        const size_t wHH = (size_t)l * Hc * Hc;
        const size_t wH  = (size_t)l * Hc;
        if (l == 0) {
            QKVArgs qa = { Wq, Wk, Wv, bq, bk, bv, qh, ql, kh, kl, vv };
            qkv0_kernel<<<dim3(24, 32), 256, 0, stream>>>(src_h, src_l, qa);
            attn_kernel<1><<<dim3(32, 16, 2), 256, 0, stream>>>(qh, ql, kh, kl, vv, ctx);
        } else {
            QKVBT qa = { wqT + wHH, wkT + wHH, wvT + wHH, bq + wH, bk + wH, bv + wH,
                         qh, kh, vv };
            qkv_bt_kernel<<<dim3(24, 32), 256, 0, stream>>>(src_h, qa);
            attn_kernel<0><<<dim3(32, 16, 2), 256, 0, stream>>>(qh, nullptr, kh, nullptr, vv, ctx);
        }
        gemm_bt_kernel<64, 0, false><<<dim3(8, 64), 256, 0, stream>>>(
            ctx, woT + wHH, bo + wH, tmp, M, Hc, Hc);
        ln_kernel<<<M, 256, 0, stream>>>(src_f, tmp, lng + wH, lnb + wH, src_f, src_h);
        gemm_bt_kernel<128, 1, true><<<dim3(32, 32), 256, 0, stream>>>(
            src_h, w1T + (size_t)l * Hc * PFc, b1 + (size_t)l * PFc, h1, M, PFc, Hc);
        gemm_bt_kernel<64, 0, false><<<dim3(8, 64), 256, 0, stream>>>(
            h1, w2T + (size_t)l * PFc * Hc, b2 + wH, tmp, M, Hc, PFc);
        float* dst = (l == Lc - 1) ? (float*)d_out : src_f;
        ln_kernel<<<M, 256, 0, stream>>>(src_f, tmp, lng + wH, lnb + wH, dst, src_h);
    }
}

// Round 7
// 1832.111 us; speedup vs baseline: 2.9077x; 1.0529x over previous
//
#include <hip/hip_runtime.h>
#include <cstdint>

constexpr int Bc = 2, Sc = 2048, Hc = 1024, NHc = 16, HDc = 64, PFc = 4096, Lc = 6;
constexpr float EPSc = 1e-5f;
constexpr float QSC = 0.18033688011112042f;   // 0.125 * log2(e)

using f32x4  = __attribute__((ext_vector_type(4))) float;
using bf16x8 = __attribute__((ext_vector_type(8))) __bf16;
using bf16x4 = __attribute__((ext_vector_type(4))) __bf16;
using u32x4  = __attribute__((ext_vector_type(4))) unsigned;

#if __has_builtin(__builtin_amdgcn_exp2f)
#define EXP2(x) __builtin_amdgcn_exp2f(x)
#else
#define EXP2(x) exp2f(x)
#endif

__device__ __forceinline__ f32x4 mfma16(bf16x8 a, bf16x8 b, f32x4 c) {
    return __builtin_amdgcn_mfma_f32_16x16x32_bf16(a, b, c, 0, 0, 0);
}

__device__ __forceinline__ void gload_lds16(const void* g, void* l) {
    __builtin_amdgcn_global_load_lds(
        (__attribute__((address_space(1))) void*)(uintptr_t)g,
        (__attribute__((address_space(3))) void*)(uint32_t)(uintptr_t)l,
        16, 0, 0);
}

struct HL { __bf16 h, l; };
__device__ __forceinline__ HL split2(float v) {
    HL r;
    r.h = (__bf16)v;
    r.l = (__bf16)(v - (float)r.h);
    return r;
}

__device__ __forceinline__ unsigned bfbits(__bf16 x) {
    return (unsigned)__builtin_bit_cast(unsigned short, x);
}
__device__ __forceinline__ unsigned packbf(float a, float b) {
    return bfbits((__bf16)a) | (bfbits((__bf16)b) << 16);
}

// ---------------------------------------------------------------------------
// Weight convert: f32 [K][N] -> bf16 [N][K], 64x64 tiles via LDS.
// ---------------------------------------------------------------------------
__global__ __launch_bounds__(256) void wconv_kernel(
    const float* __restrict__ in, __bf16* __restrict__ out, int K, int N)
{
    __shared__ float tile[64][65];
    const int t = threadIdx.x;
    const size_t lstride = (size_t)K * N;
    const float* ip = in + (size_t)blockIdx.z * lstride;
    __bf16* op = out + (size_t)blockIdx.z * lstride;
    const int n0 = blockIdx.x * 64, k0 = blockIdx.y * 64;
    #pragma unroll
    for (int c = 0; c < 4; ++c) {
        int idx = c * 256 + t;
        int row = idx >> 4;
        int c4  = idx & 15;
        float4 v = *(const float4*)(ip + (size_t)(k0 + row) * N + n0 + c4 * 4);
        tile[row][c4 * 4 + 0] = v.x; tile[row][c4 * 4 + 1] = v.y;
        tile[row][c4 * 4 + 2] = v.z; tile[row][c4 * 4 + 3] = v.w;
    }
    __syncthreads();
    #pragma unroll
    for (int c = 0; c < 4; ++c) {
        int idx = c * 256 + t;
        int n  = idx >> 4;
        int k4 = idx & 15;
        bf16x4 hh = { (__bf16)tile[k4 * 4 + 0][n], (__bf16)tile[k4 * 4 + 1][n],
                      (__bf16)tile[k4 * 4 + 2][n], (__bf16)tile[k4 * 4 + 3][n] };
        *(bf16x4*)(op + (size_t)(n0 + n) * K + k0 + k4 * 4) = hh;
    }
}

// ---------------------------------------------------------------------------
// Embed: src = in*32 + pos ; f32 master + split bf16
// ---------------------------------------------------------------------------
__global__ __launch_bounds__(256) void embed_kernel(
    const float* __restrict__ in, const float* __restrict__ pos,
    float* __restrict__ sf, __bf16* __restrict__ sh, __bf16* __restrict__ sl)
{
    const int n4 = (Bc * Sc * Hc) / 4;
    const int pmask = (Sc * Hc / 4) - 1;
    for (int i = blockIdx.x * 256 + threadIdx.x; i < n4; i += gridDim.x * 256) {
        float4 a = ((const float4*)in)[i];
        float4 p = ((const float4*)pos)[i & pmask];
        float4 r;
        r.x = a.x * 32.f + p.x; r.y = a.y * 32.f + p.y;
        r.z = a.z * 32.f + p.z; r.w = a.w * 32.f + p.w;
        ((float4*)sf)[i] = r;
        HL e0 = split2(r.x), e1 = split2(r.y), e2 = split2(r.z), e3 = split2(r.w);
        bf16x4 hh = { e0.h, e1.h, e2.h, e3.h };
        bf16x4 ll = { e0.l, e1.l, e2.l, e3.l };
        ((bf16x4*)sh)[i] = hh;
        ((bf16x4*)sl)[i] = ll;
    }
}

// ---------------------------------------------------------------------------
// GEMM on pre-transposed bf16 weights. BM x 128 tile, BK=64, 4 waves.
// OUTMODE: 0=f32, 1=bf16.
// ---------------------------------------------------------------------------
template<int BM, int OUTMODE, bool RELU>
__global__ __launch_bounds__(256) void gemm_bt_kernel(
    const __bf16* __restrict__ A, const __bf16* __restrict__ Wt,
    const float* __restrict__ bias, void* __restrict__ out,
    int M, int N, int K)
{
    constexpr int MI = BM / 32;
    __shared__ alignas(16) __bf16 Alds[BM * 64];
    __shared__ alignas(16) __bf16 Blds[128 * 64];

    const int tid = threadIdx.x, lane = tid & 63, wave = tid >> 6;
    const int lr = lane & 15, lg = lane >> 4;
    const int m0 = blockIdx.y * BM, n0 = blockIdx.x * 128;
    const int wm = (wave >> 1) * (BM / 2), wn = (wave & 1) * 64;

    f32x4 acc[MI][4] = {};

    for (int k0 = 0; k0 < K; k0 += 64) {
        #pragma unroll
        for (int c = 0; c < BM / 32; ++c) {
            int li = c * 256 + tid;
            int row = li >> 3;
            int lcb = ((li & 7) << 4) ^ ((row & 7) << 4);
            gload_lds16(A + (size_t)(m0 + row) * K + k0 + (lcb >> 1),
                        (char*)Alds + (size_t)(c * 256 + wave * 64) * 16);
        }
        #pragma unroll
        for (int c = 0; c < 4; ++c) {
            int li = c * 256 + tid;
            int row = li >> 3;
            int lcb = ((li & 7) << 4) ^ ((row & 7) << 4);
            gload_lds16(Wt + (size_t)(n0 + row) * K + k0 + (lcb >> 1),
                        (char*)Blds + (size_t)(c * 256 + wave * 64) * 16);
        }
        __syncthreads();

        bf16x8 af[2][MI], bfr[2][4];
        #pragma unroll
        for (int ks = 0; ks < 2; ++ks) {
            #pragma unroll
            for (int i = 0; i < MI; ++i) {
                int ra = wm + i * 16 + lr;
                int pa = (ks * 64 + lg * 16) ^ ((ra & 7) << 4);
                af[ks][i] = *(const bf16x8*)((const char*)Alds + ra * 128 + pa);
            }
            #pragma unroll
            for (int i = 0; i < 4; ++i) {
                int rb = wn + i * 16 + lr;
                int pb = (ks * 64 + lg * 16) ^ ((rb & 7) << 4);
                bfr[ks][i] = *(const bf16x8*)((const char*)Blds + rb * 128 + pb);
            }
        }
        #pragma unroll
        for (int ks = 0; ks < 2; ++ks)
            #pragma unroll
            for (int mi = 0; mi < MI; ++mi)
                #pragma unroll
                for (int ni = 0; ni < 4; ++ni)
                    acc[mi][ni] = mfma16(af[ks][mi], bfr[ks][ni], acc[mi][ni]);
        __syncthreads();
    }

    #pragma unroll
    for (int ni = 0; ni < 4; ++ni) {
        int col = n0 + wn + ni * 16 + lr;
        float bv = bias[col];
        #pragma unroll
        for (int mi = 0; mi < MI; ++mi) {
            int rowb = m0 + wm + mi * 16 + lg * 4;
            #pragma unroll
            for (int r = 0; r < 4; ++r) {
                float v = acc[mi][ni][r] + bv;
                if (RELU) v = fmaxf(v, 0.f);
                size_t idx = (size_t)(rowb + r) * N + col;
                if constexpr (OUTMODE == 0) ((float*)out)[idx] = v;
                else                        ((__bf16*)out)[idx] = (__bf16)v;
            }
        }
    }
}

// ---------------------------------------------------------------------------
// Fused QKV on pre-transposed bf16 weights (layers >= 1). Head-major out.
// q is pre-scaled by QSC (scores come out in log2 units).
// ---------------------------------------------------------------------------
struct QKVBT {
    const __bf16 *wq, *wk, *wv;
    const float *bq, *bk, *bv;
    __bf16 *q, *k, *v;
};

__global__ __launch_bounds__(256) void qkv_bt_kernel(
    const __bf16* __restrict__ A, QKVBT a)
{
    constexpr int N = Hc, K = Hc;
    __shared__ alignas(16) __bf16 Alds[128 * 64];
    __shared__ alignas(16) __bf16 Blds[128 * 64];

    const int tid = threadIdx.x, lane = tid & 63, wave = tid >> 6;
    const int lr = lane & 15, lg = lane >> 4;
    const int gx = blockIdx.x;
    const int widx = gx >> 3;
    const int n0 = (gx & 7) * 128;
    const int m0 = blockIdx.y * 128;
    const int wm = (wave >> 1) * 64, wn = (wave & 1) * 64;

    const __bf16* Wt  = (widx == 0) ? a.wq : (widx == 1) ? a.wk : a.wv;
    const float* bias = (widx == 0) ? a.bq : (widx == 1) ? a.bk : a.bv;

    f32x4 acc[4][4] = {};

    for (int k0 = 0; k0 < K; k0 += 64) {
        #pragma unroll
        for (int c = 0; c < 4; ++c) {
            int li = c * 256 + tid;
            int row = li >> 3;
            int lcb = ((li & 7) << 4) ^ ((row & 7) << 4);
            gload_lds16(A + (size_t)(m0 + row) * K + k0 + (lcb >> 1),
                        (char*)Alds + (size_t)(c * 256 + wave * 64) * 16);
            gload_lds16(Wt + (size_t)(n0 + row) * K + k0 + (lcb >> 1),
                        (char*)Blds + (size_t)(c * 256 + wave * 64) * 16);
        }
        __syncthreads();

        bf16x8 af[2][4], bfr[2][4];
        #pragma unroll
        for (int ks = 0; ks < 2; ++ks) {
            #pragma unroll
            for (int i = 0; i < 4; ++i) {
                int ra = wm + i * 16 + lr;
                int pa = (ks * 64 + lg * 16) ^ ((ra & 7) << 4);
                af[ks][i] = *(const bf16x8*)((const char*)Alds + ra * 128 + pa);
                int rb = wn + i * 16 + lr;
                int pb = (ks * 64 + lg * 16) ^ ((rb & 7) << 4);
                bfr[ks][i] = *(const bf16x8*)((const char*)Blds + rb * 128 + pb);
            }
        }
        #pragma unroll
        for (int ks = 0; ks < 2; ++ks)
            #pragma unroll
            for (int mi = 0; mi < 4; ++mi)
                #pragma unroll
                for (int ni = 0; ni < 4; ++ni)
                    acc[mi][ni] = mfma16(af[ks][mi], bfr[ks][ni], acc[mi][ni]);
        __syncthreads();
    }

    __bf16* outp = (widx == 0) ? a.q : (widx == 1) ? a.k : a.v;
    const float osc = (widx == 0) ? QSC : 1.f;
    #pragma unroll
    for (int ni = 0; ni < 4; ++ni) {
        int col = n0 + wn + ni * 16 + lr;
        float bv = bias[col];
        int hh = col >> 6, d = col & 63;
        #pragma unroll
        for (int mi = 0; mi < 4; ++mi) {
            int rowb = m0 + wm + mi * 16 + lg * 4;
            #pragma unroll
            for (int r = 0; r < 4; ++r) {
                int row = rowb + r;
                int bb = row >> 11, s = row & (Sc - 1);
                outp[((size_t)(bb * NHc + hh) * Sc + s) * HDc + d] =
                    (__bf16)((acc[mi][ni][r] + bv) * osc);
            }
        }
    }
}

// ---------------------------------------------------------------------------
// Layer-0 QKV (full split precision, f32 weights). Head-major out, q/k hi+lo.
// q scaled by QSC in f32 BEFORE split (preserves split accuracy).
// ---------------------------------------------------------------------------
struct QKVArgs {
    const float *Wq, *Wk, *Wv, *bq, *bk, *bv;
    __bf16 *qh, *ql, *kh, *kl, *vv;
};

__global__ __launch_bounds__(256) void qkv0_kernel(
    const __bf16* __restrict__ Ahi, const __bf16* __restrict__ Alo, QKVArgs a)
{
    constexpr int N = Hc, K = Hc;
    __shared__ alignas(16) __bf16 AldsH[128 * 64];
    __shared__ alignas(16) __bf16 AldsL[128 * 64];
    __shared__ alignas(16) __bf16 BldsH[128 * 64];
    __shared__ alignas(16) __bf16 BldsL[128 * 64];

    const int tid  = threadIdx.x;
    const int lane = tid & 63;
    const int wave = tid >> 6;
    const int lr   = lane & 15;
    const int lg   = lane >> 4;
    const int gx   = blockIdx.x;
    const int widx = gx >> 3;
    const int n0   = (gx & 7) * 128;
    const int m0   = blockIdx.y * 128;
    const int wm   = (wave >> 1) * 64;
    const int wn   = (wave & 1) * 64;
    const int bn   = tid & 127;
    const int bkh  = (tid >> 7) * 32;

    const float* Bw   = (widx == 0) ? a.Wq : (widx == 1) ? a.Wk : a.Wv;
    const float* bias = (widx == 0) ? a.bq : (widx == 1) ? a.bk : a.bv;

    f32x4 acc[4][4] = {};
    const float* bsrc0 = Bw + (size_t)bkh * N + n0 + bn;

    for (int k0 = 0; k0 < K; k0 += 64) {
        #pragma unroll
        for (int c = 0; c < 4; ++c) {
            int li  = c * 256 + tid;
            int row = li >> 3;
            int lcb = ((li & 7) << 4) ^ ((row & 7) << 4);
            size_t goff = (size_t)(m0 + row) * K + k0 + (lcb >> 1);
            size_t loff = (size_t)(c * 256 + wave * 64) * 16;
            gload_lds16(Ahi + goff, (char*)AldsH + loff);
            gload_lds16(Alo + goff, (char*)AldsL + loff);
        }
        const float* bs = bsrc0 + (size_t)k0 * N;
        #pragma unroll
        for (int c = 0; c < 4; ++c) {
            bf16x8 ph, plv;
            #pragma unroll
            for (int j = 0; j < 8; ++j) {
                HL e = split2(bs[(size_t)(c * 8 + j) * N]);
                ph[j] = e.h;
                plv[j] = e.l;
            }
            int pcb = (bkh * 2 + c * 16) ^ ((bn & 7) << 4);
            *(bf16x8*)((char*)BldsH + bn * 128 + pcb) = ph;
            *(bf16x8*)((char*)BldsL + bn * 128 + pcb) = plv;
        }
        __syncthreads();

        bf16x8 ah[2][4], al[2][4], bh[2][4], bl[2][4];
        #pragma unroll
        for (int ks = 0; ks < 2; ++ks) {
            #pragma unroll
            for (int i = 0; i < 4; ++i) {
                int ra = wm + i * 16 + lr;
                int pa = (ks * 64 + lg * 16) ^ ((ra & 7) << 4);
                ah[ks][i] = *(const bf16x8*)((const char*)AldsH + ra * 128 + pa);
                al[ks][i] = *(const bf16x8*)((const char*)AldsL + ra * 128 + pa);
                int rb = wn + i * 16 + lr;
                int pb = (ks * 64 + lg * 16) ^ ((rb & 7) << 4);
                bh[ks][i] = *(const bf16x8*)((const char*)BldsH + rb * 128 + pb);
                bl[ks][i] = *(const bf16x8*)((const char*)BldsL + rb * 128 + pb);
            }
        }
        #pragma unroll
        for (int ks = 0; ks < 2; ++ks)
            #pragma unroll
            for (int mi = 0; mi < 4; ++mi)
                #pragma unroll
                for (int ni = 0; ni < 4; ++ni) {
                    acc[mi][ni] = mfma16(ah[ks][mi], bh[ks][ni], acc[mi][ni]);
                    acc[mi][ni] = mfma16(al[ks][mi], bh[ks][ni], acc[mi][ni]);
                    acc[mi][ni] = mfma16(ah[ks][mi], bl[ks][ni], acc[mi][ni]);
                }
        __syncthreads();
    }

    __bf16* outh = (widx == 0) ? a.qh : (widx == 1) ? a.kh : a.vv;
    __bf16* outl = (widx == 0) ? a.ql : a.kl;
    const float osc = (widx == 0) ? QSC : 1.f;
    #pragma unroll
    for (int ni = 0; ni < 4; ++ni) {
        int col = n0 + wn + ni * 16 + lr;
        float bv = bias[col];
        int hh = col >> 6, d = col & 63;
        #pragma unroll
        for (int mi = 0; mi < 4; ++mi) {
            int rowb = m0 + wm + mi * 16 + lg * 4;
            #pragma unroll
            for (int r = 0; r < 4; ++r) {
                int row = rowb + r;
                int bb = row >> 11, s = row & (Sc - 1);
                size_t idx = ((size_t)(bb * NHc + hh) * Sc + s) * HDc + d;
                float v = (acc[mi][ni][r] + bv) * osc;
                if (widx < 2) {
                    HL e = split2(v);
                    outh[idx] = e.h;
                    outl[idx] = e.l;
                } else {
                    outh[idx] = (__bf16)v;
                }
            }
        }
    }
}

// ---------------------------------------------------------------------------
// Flash attention v3. Scores arrive in log2 units (q pre-scaled by QSC).
// exp2 direct; defer-max THR=8 (softmax-invariant). Key-slot permutation
// keeps PV A-operand lane-local; V permuted+transposed in LDS (conflict-free
// b32 writes). K/VT double-buffered, next-tile loads issued before compute.
// ---------------------------------------------------------------------------
template<int QKSPLIT>
__global__ __launch_bounds__(256) void attn_kernel(
    const __bf16* __restrict__ Qh, const __bf16* __restrict__ Ql,
    const __bf16* __restrict__ Kh, const __bf16* __restrict__ Kl,
    const __bf16* __restrict__ V, __bf16* __restrict__ O)
{
    __shared__ alignas(16) __bf16 Ksh[2][64 * 64];
    __shared__ alignas(16) __bf16 Klo[QKSPLIT ? 2 : 1][QKSPLIT ? 64 * 64 : 8];
    __shared__ alignas(16) __bf16 VT[2][64 * 64];

    const int tid = threadIdx.x;
    const int lane = tid & 63, wave = tid >> 6;
    const int lr = lane & 15, lg = lane >> 4;
    const int h = blockIdx.y, b = blockIdx.z;
    const int q0 = blockIdx.x * 64 + wave * 16;

    const size_t headoff = ((size_t)b * NHc + h) * Sc * HDc;
    const __bf16* Qb  = Qh + headoff;
    const __bf16* Kb  = Kh + headoff;
    const __bf16* Klb = QKSPLIT ? (Kl + headoff) : nullptr;
    const __bf16* Vb  = V + headoff;

    const size_t qrow = (size_t)(q0 + lr) * HDc;
    bf16x8 qf0 = *(const bf16x8*)(Qb + qrow + lg * 8);
    bf16x8 qf1 = *(const bf16x8*)(Qb + qrow + 32 + lg * 8);
    bf16x8 qlo0, qlo1;
    if constexpr (QKSPLIT) {
        const __bf16* Qlb = Ql + headoff;
        qlo0 = *(const bf16x8*)(Qlb + qrow + lg * 8);
        qlo1 = *(const bf16x8*)(Qlb + qrow + 32 + lg * 8);
    }

    const int kp = tid & 31, dblk = tid >> 5;
    const int sp = (kp & 0x11) | ((kp & 0x06) << 1) | ((kp & 0x08) >> 2);

    auto stageK = [&](int kt, int buf) {
        #pragma unroll
        for (int c = 0; c < 2; ++c) {
            int li  = c * 256 + tid;
            int row = li >> 3;
            int lcb = ((li & 7) << 4) ^ ((row & 7) << 4);
            size_t goff = (size_t)(kt * 64 + row) * HDc + (lcb >> 1);
            size_t loff = (size_t)(c * 256 + wave * 64) * 16;
            gload_lds16(Kb + goff, (char*)Ksh[buf] + loff);
            if constexpr (QKSPLIT)
                gload_lds16(Klb + goff, (char*)Klo[buf] + loff);
        }
    };
    auto loadV = [&](int kt, bf16x8& va, bf16x8& vb2) {
        const __bf16* vs = Vb + (size_t)(kt * 64 + 2 * kp) * HDc + dblk * 8;
        va  = *(const bf16x8*)vs;
        vb2 = *(const bf16x8*)(vs + HDc);
    };
    auto writeVT = [&](int buf, bf16x8 va, bf16x8 vb2) {
        #pragma unroll
        for (int j = 0; j < 8; ++j) {
            int d = dblk * 8 + j;
            unsigned u = bfbits(va[j]) | (bfbits(vb2[j]) << 16);
            int byte = d * 128 + ((sp * 4) ^ ((d & 7) << 4));
            *(unsigned*)((char*)VT[buf] + byte) = u;
        }
    };

    f32x4 o[4] = {};
    float m = -1e30f, lsum = 0.f;

    stageK(0, 0);
    {
        bf16x8 va, vb2;
        loadV(0, va, vb2);
        writeVT(0, va, vb2);
    }
    __syncthreads();

    int cur = 0;
    for (int kt = 0; kt < Sc / 64; ++kt) {
        const int nb = cur ^ 1;
        const bool pf = (kt + 1 < Sc / 64);
        bf16x8 va, vb2;
        if (pf) {
            stageK(kt + 1, nb);
            loadV(kt + 1, va, vb2);
        }

        // ---- QK^T (scores already in log2 units) ----
        const char* Kc = (const char*)Ksh[cur];
        const char* Klc = (const char*)Klo[QKSPLIT ? cur : 0];
        f32x4 s[4];
        #pragma unroll
        for (int kg = 0; kg < 4; ++kg) {
            int ra = kg * 16 + lr;
            int pa0 = (lg * 16) ^ ((ra & 7) << 4);
            int pa1 = (64 + lg * 16) ^ ((ra & 7) << 4);
            bf16x8 kf0 = *(const bf16x8*)(Kc + ra * 128 + pa0);
            bf16x8 kf1 = *(const bf16x8*)(Kc + ra * 128 + pa1);
            f32x4 t = {};
            t = mfma16(kf0, qf0, t);
            t = mfma16(kf1, qf1, t);
            if constexpr (QKSPLIT) {
                bf16x8 kg0 = *(const bf16x8*)(Klc + ra * 128 + pa0);
                bf16x8 kg1 = *(const bf16x8*)(Klc + ra * 128 + pa1);
                t = mfma16(kg0, qf0, t);
                t = mfma16(kg1, qf1, t);
                t = mfma16(kf0, qlo0, t);
                t = mfma16(kf1, qlo1, t);
            }
            s[kg] = t;
        }

        // ---- online softmax (base 2) ----
        float mt = -1e30f;
        #pragma unroll
        for (int kg = 0; kg < 4; ++kg)
            #pragma unroll
            for (int r = 0; r < 4; ++r)
                mt = fmaxf(mt, s[kg][r]);
        mt = fmaxf(mt, __shfl_xor(mt, 16));
        mt = fmaxf(mt, __shfl_xor(mt, 32));
        if (!__all(mt <= m + 8.f)) {     // defer-max: p bounded by 2^8
            float mnew = fmaxf(m, mt);
            float fac = EXP2(m - mnew);
            m = mnew;
            lsum *= fac;
            #pragma unroll
            for (int r = 0; r < 4; ++r) {
                float fr = __shfl(fac, (lg << 4) | (lg * 4 + r));
                #pragma unroll
                for (int nd = 0; nd < 4; ++nd) o[nd][r] *= fr;
            }
        }
        float ps = 0.f;
        #pragma unroll
        for (int kg = 0; kg < 4; ++kg)
            #pragma unroll
            for (int r = 0; r < 4; ++r) {
                float p = EXP2(s[kg][r] - m);
                ps += p;
                s[kg][r] = p;
            }
        ps += __shfl_xor(ps, 16);
        ps += __shfl_xor(ps, 32);
        lsum += ps;

        // ---- PV: A-operand lane-local via slot permutation ----
        #pragma unroll
        for (int kh2 = 0; kh2 < 2; ++kh2) {
            u32x4 pk;
            pk[0] = packbf(s[2 * kh2][0],     s[2 * kh2][1]);
            pk[1] = packbf(s[2 * kh2][2],     s[2 * kh2][3]);
            pk[2] = packbf(s[2 * kh2 + 1][0], s[2 * kh2 + 1][1]);
            pk[3] = packbf(s[2 * kh2 + 1][2], s[2 * kh2 + 1][3]);
            bf16x8 paf = __builtin_bit_cast(bf16x8, pk);
            #pragma unroll
            for (int nd = 0; nd < 4; ++nd) {
                int d = nd * 16 + lr;
                int byte = d * 128 + ((64 * kh2 + 16 * lg) ^ ((d & 7) << 4));
                bf16x8 vbf = *(const bf16x8*)((const char*)VT[cur] + byte);
                o[nd] = mfma16(paf, vbf, o[nd]);
            }
        }

        if (pf) writeVT(nb, va, vb2);
        __syncthreads();
        cur = nb;
    }

    // ---- epilogue: row-major ctx [B,S,H] ----
    #pragma unroll
    for (int r = 0; r < 4; ++r) {
        float lv  = __shfl(lsum, (lg << 4) | (lg * 4 + r));
        float inv = 1.f / lv;
        size_t orow = ((size_t)b * Sc + q0 + lg * 4 + r) * Hc + h * HDc;
        #pragma unroll
        for (int nd = 0; nd < 4; ++nd)
            O[orow + nd * 16 + lr] = (__bf16)(o[nd][r] * inv);
    }
}

// ---------------------------------------------------------------------------
// Fused residual + LayerNorm: y now bf16. f32 master + bf16 copy out.
// ---------------------------------------------------------------------------
__global__ __launch_bounds__(256) void ln_kernel(
    const float* __restrict__ xr, const __bf16* __restrict__ y,
    const float* __restrict__ g, const float* __restrict__ beta,
    float* __restrict__ of, __bf16* __restrict__ oh)
{
    __shared__ float red[2][4];
    const int row = blockIdx.x, t = threadIdx.x;
    const int lane = t & 63, wave = t >> 6;
    const int idx = row * 256 + t;
    float4 a = ((const float4*)xr)[idx];
    bf16x4 cb = ((const bf16x4*)y)[idx];
    float4 v;
    v.x = a.x + (float)cb[0]; v.y = a.y + (float)cb[1];
    v.z = a.z + (float)cb[2]; v.w = a.w + (float)cb[3];
    float s1 = v.x + v.y + v.z + v.w;
    float s2 = v.x * v.x + v.y * v.y + v.z * v.z + v.w * v.w;
    #pragma unroll
    for (int off = 1; off < 64; off <<= 1) {
        s1 += __shfl_xor(s1, off);
        s2 += __shfl_xor(s2, off);
    }
    if (lane == 0) { red[0][wave] = s1; red[1][wave] = s2; }
    __syncthreads();
    s1 = red[0][0] + red[0][1] + red[0][2] + red[0][3];
    s2 = red[1][0] + red[1][1] + red[1][2] + red[1][3];
    const float mu   = s1 * (1.f / Hc);
    const float var  = s2 * (1.f / Hc) - mu * mu;
    const float rstd = rsqrtf(var + EPSc);
    float4 gg = ((const float4*)g)[t];
    float4 bb = ((const float4*)beta)[t];
    float4 r;
    r.x = (v.x - mu) * rstd * gg.x + bb.x;
    r.y = (v.y - mu) * rstd * gg.y + bb.y;
    r.z = (v.z - mu) * rstd * gg.z + bb.z;
    r.w = (v.w - mu) * rstd * gg.w + bb.w;
    ((float4*)of)[idx] = r;
    bf16x4 hh = { (__bf16)r.x, (__bf16)r.y, (__bf16)r.z, (__bf16)r.w };
    ((bf16x4*)oh)[idx] = hh;
}

// ---------------------------------------------------------------------------
extern "C" void kernel_launch(void* const* d_in, const int* in_sizes, int n_in,
                              void* d_out, int out_size, void* d_ws, size_t ws_size,
                              hipStream_t stream)
{
    const float* inp = (const float*)d_in[0];
    const float* pos = (const float*)d_in[1];
    const float* Wq  = (const float*)d_in[2];
    const float* bq  = (const float*)d_in[3];
    const float* Wk  = (const float*)d_in[4];
    const float* bk  = (const float*)d_in[5];
    const float* Wv  = (const float*)d_in[6];
    const float* bv  = (const float*)d_in[7];
    const float* Wo  = (const float*)d_in[8];
    const float* bo  = (const float*)d_in[9];
    const float* lng = (const float*)d_in[10];
    const float* lnb = (const float*)d_in[11];
    const float* W1  = (const float*)d_in[12];
    const float* b1  = (const float*)d_in[13];
    const float* W2  = (const float*)d_in[14];
    const float* b2  = (const float*)d_in[15];

    char* ws = (char*)d_ws;
    const size_t MB = 1u << 20;
    float*  src_f = (float*)(ws);              // 16 MB
    __bf16* src_h = (__bf16*)(ws + 16 * MB);   //  8 MB
    __bf16* src_l = (__bf16*)(ws + 24 * MB);   //  8 MB
    __bf16* qh    = (__bf16*)(ws + 32 * MB);   //  8 MB (head-major)
    __bf16* kh    = (__bf16*)(ws + 40 * MB);   //  8 MB
    __bf16* vv    = (__bf16*)(ws + 48 * MB);   //  8 MB
    __bf16* ctx   = (__bf16*)(ws + 56 * MB);   //  8 MB (row-major)
    __bf16* ql    = (__bf16*)(ws + 64 * MB);   //  8 MB (layer 0 only)
    __bf16* kl    = (__bf16*)(ws + 72 * MB);   //  8 MB
    __bf16* tmpb  = (__bf16*)(ws + 80 * MB);   //  8 MB (bf16 GEMM out)
    __bf16* h1    = (__bf16*)(ws + 32 * MB);   // 32 MB alias (qh..ctx, dead by FFN)
    __bf16* wqT   = (__bf16*)(ws + 96 * MB);   // 12 MB each
    __bf16* wkT   = (__bf16*)(ws + 108 * MB);
    __bf16* wvT   = (__bf16*)(ws + 120 * MB);
    __bf16* woT   = (__bf16*)(ws + 132 * MB);
    __bf16* w1T   = (__bf16*)(ws + 144 * MB);  // 48 MB
    __bf16* w2T   = (__bf16*)(ws + 192 * MB);  // 48 MB ; total 240 MB

    const int M = Bc * Sc;  // 4096

    wconv_kernel<<<dim3(16, 16, 6), 256, 0, stream>>>(Wq, wqT, Hc, Hc);
    wconv_kernel<<<dim3(16, 16, 6), 256, 0, stream>>>(Wk, wkT, Hc, Hc);
    wconv_kernel<<<dim3(16, 16, 6), 256, 0, stream>>>(Wv, wvT, Hc, Hc);
    wconv_kernel<<<dim3(16, 16, 6), 256, 0, stream>>>(Wo, woT, Hc, Hc);
    wconv_kernel<<<dim3(64, 16, 6), 256, 0, stream>>>(W1, w1T, Hc, PFc);
    wconv_kernel<<<dim3(16, 64, 6), 256, 0, stream>>>(W2, w2T, PFc, Hc);

    embed_kernel<<<2048, 256, 0, stream>>>(inp, pos, src_f, src_h, src_l);

    for (int l = 0; l < Lc; ++l) {
        const size_t wHH = (size_t)l * Hc * Hc;
        const size_t wH  = (size_t)l * Hc;
        if (l == 0) {
            QKVArgs qa = { Wq, Wk, Wv, bq, bk, bv, qh, ql, kh, kl, vv };
            qkv0_kernel<<<dim3(24, 32), 256, 0, stream>>>(src_h, src_l, qa);
            attn_kernel<1><<<dim3(32, 16, 2), 256, 0, stream>>>(qh, ql, kh, kl, vv, ctx);
        } else {
            QKVBT qa = { wqT + wHH, wkT + wHH, wvT + wHH, bq + wH, bk + wH, bv + wH,
                         qh, kh, vv };
            qkv_bt_kernel<<<dim3(24, 32), 256, 0, stream>>>(src_h, qa);
            attn_kernel<0><<<dim3(32, 16, 2), 256, 0, stream>>>(qh, nullptr, kh, nullptr, vv, ctx);
        }
        gemm_bt_kernel<64, 1, false><<<dim3(8, 64), 256, 0, stream>>>(
            ctx, woT + wHH, bo + wH, tmpb, M, Hc, Hc);
        ln_kernel<<<M, 256, 0, stream>>>(src_f, tmpb, lng + wH, lnb + wH, src_f, src_h);
        gemm_bt_kernel<128, 1, true><<<dim3(32, 32), 256, 0, stream>>>(
            src_h, w1T + (size_t)l * Hc * PFc, b1 + (size_t)l * PFc, h1, M, PFc, Hc);
        gemm_bt_kernel<64, 1, false><<<dim3(8, 64), 256, 0, stream>>>(
            h1, w2T + (size_t)l * PFc * Hc, b2 + wH, tmpb, M, Hc, PFc);
        float* dst = (l == Lc - 1) ? (float*)d_out : src_f;
        ln_kernel<<<M, 256, 0, stream>>>(src_f, tmpb, lng + wH, lnb + wH, dst, src_h);
    }
}

// Round 8
// 1707.057 us; speedup vs baseline: 3.1207x; 1.0733x over previous
//
#include <hip/hip_runtime.h>
#include <cstdint>

constexpr int Bc = 2, Sc = 2048, Hc = 1024, NHc = 16, HDc = 64, PFc = 4096, Lc = 6;
constexpr float EPSc = 1e-5f;
constexpr float QSC = 0.18033688011112042f;   // 0.125 * log2(e)

using f32x4  = __attribute__((ext_vector_type(4))) float;
using bf16x8 = __attribute__((ext_vector_type(8))) __bf16;
using bf16x4 = __attribute__((ext_vector_type(4))) __bf16;
using u32x4  = __attribute__((ext_vector_type(4))) unsigned;

#if __has_builtin(__builtin_amdgcn_exp2f)
#define EXP2(x) __builtin_amdgcn_exp2f(x)
#else
#define EXP2(x) exp2f(x)
#endif

__device__ __forceinline__ f32x4 mfma16(bf16x8 a, bf16x8 b, f32x4 c) {
    return __builtin_amdgcn_mfma_f32_16x16x32_bf16(a, b, c, 0, 0, 0);
}

__device__ __forceinline__ void gload_lds16(const void* g, void* l) {
    __builtin_amdgcn_global_load_lds(
        (__attribute__((address_space(1))) void*)(uintptr_t)g,
        (__attribute__((address_space(3))) void*)(uint32_t)(uintptr_t)l,
        16, 0, 0);
}

struct HL { __bf16 h, l; };
__device__ __forceinline__ HL split2(float v) {
    HL r;
    r.h = (__bf16)v;
    r.l = (__bf16)(v - (float)r.h);
    return r;
}

__device__ __forceinline__ unsigned bfbits(__bf16 x) {
    return (unsigned)__builtin_bit_cast(unsigned short, x);
}
__device__ __forceinline__ unsigned packbf(float a, float b) {
    return bfbits((__bf16)a) | (bfbits((__bf16)b) << 16);
}

// ---------------------------------------------------------------------------
// Weight convert: f32 [K][N] -> bf16 [N][K], 64x64 tiles via LDS.
// ---------------------------------------------------------------------------
__global__ __launch_bounds__(256) void wconv_kernel(
    const float* __restrict__ in, __bf16* __restrict__ out, int K, int N)
{
    __shared__ float tile[64][65];
    const int t = threadIdx.x;
    const size_t lstride = (size_t)K * N;
    const float* ip = in + (size_t)blockIdx.z * lstride;
    __bf16* op = out + (size_t)blockIdx.z * lstride;
    const int n0 = blockIdx.x * 64, k0 = blockIdx.y * 64;
    #pragma unroll
    for (int c = 0; c < 4; ++c) {
        int idx = c * 256 + t;
        int row = idx >> 4;
        int c4  = idx & 15;
        float4 v = *(const float4*)(ip + (size_t)(k0 + row) * N + n0 + c4 * 4);
        tile[row][c4 * 4 + 0] = v.x; tile[row][c4 * 4 + 1] = v.y;
        tile[row][c4 * 4 + 2] = v.z; tile[row][c4 * 4 + 3] = v.w;
    }
    __syncthreads();
    #pragma unroll
    for (int c = 0; c < 4; ++c) {
        int idx = c * 256 + t;
        int n  = idx >> 4;
        int k4 = idx & 15;
        bf16x4 hh = { (__bf16)tile[k4 * 4 + 0][n], (__bf16)tile[k4 * 4 + 1][n],
                      (__bf16)tile[k4 * 4 + 2][n], (__bf16)tile[k4 * 4 + 3][n] };
        *(bf16x4*)(op + (size_t)(n0 + n) * K + k0 + k4 * 4) = hh;
    }
}

// ---------------------------------------------------------------------------
// Embed: src = in*32 + pos ; f32 master + split bf16
// ---------------------------------------------------------------------------
__global__ __launch_bounds__(256) void embed_kernel(
    const float* __restrict__ in, const float* __restrict__ pos,
    float* __restrict__ sf, __bf16* __restrict__ sh, __bf16* __restrict__ sl)
{
    const int n4 = (Bc * Sc * Hc) / 4;
    const int pmask = (Sc * Hc / 4) - 1;
    for (int i = blockIdx.x * 256 + threadIdx.x; i < n4; i += gridDim.x * 256) {
        float4 a = ((const float4*)in)[i];
        float4 p = ((const float4*)pos)[i & pmask];
        float4 r;
        r.x = a.x * 32.f + p.x; r.y = a.y * 32.f + p.y;
        r.z = a.z * 32.f + p.z; r.w = a.w * 32.f + p.w;
        ((float4*)sf)[i] = r;
        HL e0 = split2(r.x), e1 = split2(r.y), e2 = split2(r.z), e3 = split2(r.w);
        bf16x4 hh = { e0.h, e1.h, e2.h, e3.h };
        bf16x4 ll = { e0.l, e1.l, e2.l, e3.l };
        ((bf16x4*)sh)[i] = hh;
        ((bf16x4*)sl)[i] = ll;
    }
}

// ---------------------------------------------------------------------------
// GEMM on pre-transposed bf16 weights. BM x 128 tile, BK=64, 4 waves.
// 2-phase pipeline (T3 minimum): double-buffered LDS, next-tile stage issued
// BEFORE current-tile compute, ONE barrier per K-step (vmcnt(0) folded in).
// OUTMODE: 0=f32, 1=bf16.
// ---------------------------------------------------------------------------
template<int BM, int OUTMODE, bool RELU>
__global__ __launch_bounds__(256) void gemm_bt_kernel(
    const __bf16* __restrict__ A, const __bf16* __restrict__ Wt,
    const float* __restrict__ bias, void* __restrict__ out,
    int M, int N, int K)
{
    constexpr int MI = BM / 32;
    __shared__ alignas(16) __bf16 Alds[2][BM * 64];
    __shared__ alignas(16) __bf16 Blds[2][128 * 64];

    const int tid = threadIdx.x, lane = tid & 63, wave = tid >> 6;
    const int lr = lane & 15, lg = lane >> 4;
    const int m0 = blockIdx.y * BM, n0 = blockIdx.x * 128;
    const int wm = (wave >> 1) * (BM / 2), wn = (wave & 1) * 64;

    f32x4 acc[MI][4] = {};

    auto stage = [&](int k0, int buf) {
        #pragma unroll
        for (int c = 0; c < BM / 32; ++c) {
            int li = c * 256 + tid;
            int row = li >> 3;
            int lcb = ((li & 7) << 4) ^ ((row & 7) << 4);
            gload_lds16(A + (size_t)(m0 + row) * K + k0 + (lcb >> 1),
                        (char*)Alds[buf] + (size_t)(c * 256 + wave * 64) * 16);
        }
        #pragma unroll
        for (int c = 0; c < 4; ++c) {
            int li = c * 256 + tid;
            int row = li >> 3;
            int lcb = ((li & 7) << 4) ^ ((row & 7) << 4);
            gload_lds16(Wt + (size_t)(n0 + row) * K + k0 + (lcb >> 1),
                        (char*)Blds[buf] + (size_t)(c * 256 + wave * 64) * 16);
        }
    };

    stage(0, 0);
    __syncthreads();                 // vmcnt(0) drain + barrier
    int cur = 0;

    for (int k0 = 0; k0 < K; k0 += 64) {
        if (k0 + 64 < K) stage(k0 + 64, cur ^ 1);   // issue early, lands late

        bf16x8 af[2][MI], bfr[2][4];
        #pragma unroll
        for (int ks = 0; ks < 2; ++ks) {
            #pragma unroll
            for (int i = 0; i < MI; ++i) {
                int ra = wm + i * 16 + lr;
                int pa = (ks * 64 + lg * 16) ^ ((ra & 7) << 4);
                af[ks][i] = *(const bf16x8*)((const char*)Alds[cur] + ra * 128 + pa);
            }
            #pragma unroll
            for (int i = 0; i < 4; ++i) {
                int rb = wn + i * 16 + lr;
                int pb = (ks * 64 + lg * 16) ^ ((rb & 7) << 4);
                bfr[ks][i] = *(const bf16x8*)((const char*)Blds[cur] + rb * 128 + pb);
            }
        }
        #pragma unroll
        for (int ks = 0; ks < 2; ++ks)
            #pragma unroll
            for (int mi = 0; mi < MI; ++mi)
                #pragma unroll
                for (int ni = 0; ni < 4; ++ni)
                    acc[mi][ni] = mfma16(af[ks][mi], bfr[ks][ni], acc[mi][ni]);

        __syncthreads();             // single barrier: drains stage + orders
        cur ^= 1;
    }

    #pragma unroll
    for (int ni = 0; ni < 4; ++ni) {
        int col = n0 + wn + ni * 16 + lr;
        float bv = bias[col];
        #pragma unroll
        for (int mi = 0; mi < MI; ++mi) {
            int rowb = m0 + wm + mi * 16 + lg * 4;
            #pragma unroll
            for (int r = 0; r < 4; ++r) {
                float v = acc[mi][ni][r] + bv;
                if (RELU) v = fmaxf(v, 0.f);
                size_t idx = (size_t)(rowb + r) * N + col;
                if constexpr (OUTMODE == 0) ((float*)out)[idx] = v;
                else                        ((__bf16*)out)[idx] = (__bf16)v;
            }
        }
    }
}

// ---------------------------------------------------------------------------
// Fused QKV on pre-transposed bf16 weights (layers >= 1). Head-major out.
// Same 2-phase pipeline. q pre-scaled by QSC.
// ---------------------------------------------------------------------------
struct QKVBT {
    const __bf16 *wq, *wk, *wv;
    const float *bq, *bk, *bv;
    __bf16 *q, *k, *v;
};

__global__ __launch_bounds__(256) void qkv_bt_kernel(
    const __bf16* __restrict__ A, QKVBT a)
{
    constexpr int N = Hc, K = Hc;
    __shared__ alignas(16) __bf16 Alds[2][128 * 64];
    __shared__ alignas(16) __bf16 Blds[2][128 * 64];

    const int tid = threadIdx.x, lane = tid & 63, wave = tid >> 6;
    const int lr = lane & 15, lg = lane >> 4;
    const int gx = blockIdx.x;
    const int widx = gx >> 3;
    const int n0 = (gx & 7) * 128;
    const int m0 = blockIdx.y * 128;
    const int wm = (wave >> 1) * 64, wn = (wave & 1) * 64;

    const __bf16* Wt  = (widx == 0) ? a.wq : (widx == 1) ? a.wk : a.wv;
    const float* bias = (widx == 0) ? a.bq : (widx == 1) ? a.bk : a.bv;

    f32x4 acc[4][4] = {};

    auto stage = [&](int k0, int buf) {
        #pragma unroll
        for (int c = 0; c < 4; ++c) {
            int li = c * 256 + tid;
            int row = li >> 3;
            int lcb = ((li & 7) << 4) ^ ((row & 7) << 4);
            gload_lds16(A + (size_t)(m0 + row) * K + k0 + (lcb >> 1),
                        (char*)Alds[buf] + (size_t)(c * 256 + wave * 64) * 16);
            gload_lds16(Wt + (size_t)(n0 + row) * K + k0 + (lcb >> 1),
                        (char*)Blds[buf] + (size_t)(c * 256 + wave * 64) * 16);
        }
    };

    stage(0, 0);
    __syncthreads();
    int cur = 0;

    for (int k0 = 0; k0 < K; k0 += 64) {
        if (k0 + 64 < K) stage(k0 + 64, cur ^ 1);

        bf16x8 af[2][4], bfr[2][4];
        #pragma unroll
        for (int ks = 0; ks < 2; ++ks) {
            #pragma unroll
            for (int i = 0; i < 4; ++i) {
                int ra = wm + i * 16 + lr;
                int pa = (ks * 64 + lg * 16) ^ ((ra & 7) << 4);
                af[ks][i] = *(const bf16x8*)((const char*)Alds[cur] + ra * 128 + pa);
                int rb = wn + i * 16 + lr;
                int pb = (ks * 64 + lg * 16) ^ ((rb & 7) << 4);
                bfr[ks][i] = *(const bf16x8*)((const char*)Blds[cur] + rb * 128 + pb);
            }
        }
        #pragma unroll
        for (int ks = 0; ks < 2; ++ks)
            #pragma unroll
            for (int mi = 0; mi < 4; ++mi)
                #pragma unroll
                for (int ni = 0; ni < 4; ++ni)
                    acc[mi][ni] = mfma16(af[ks][mi], bfr[ks][ni], acc[mi][ni]);

        __syncthreads();
        cur ^= 1;
    }

    __bf16* outp = (widx == 0) ? a.q : (widx == 1) ? a.k : a.v;
    const float osc = (widx == 0) ? QSC : 1.f;
    #pragma unroll
    for (int ni = 0; ni < 4; ++ni) {
        int col = n0 + wn + ni * 16 + lr;
        float bv = bias[col];
        int hh = col >> 6, d = col & 63;
        #pragma unroll
        for (int mi = 0; mi < 4; ++mi) {
            int rowb = m0 + wm + mi * 16 + lg * 4;
            #pragma unroll
            for (int r = 0; r < 4; ++r) {
                int row = rowb + r;
                int bb = row >> 11, s = row & (Sc - 1);
                outp[((size_t)(bb * NHc + hh) * Sc + s) * HDc + d] =
                    (__bf16)((acc[mi][ni][r] + bv) * osc);
            }
        }
    }
}

// ---------------------------------------------------------------------------
// Layer-0 QKV (full split precision, f32 weights). Head-major out, q/k hi+lo.
// ---------------------------------------------------------------------------
struct QKVArgs {
    const float *Wq, *Wk, *Wv, *bq, *bk, *bv;
    __bf16 *qh, *ql, *kh, *kl, *vv;
};

__global__ __launch_bounds__(256) void qkv0_kernel(
    const __bf16* __restrict__ Ahi, const __bf16* __restrict__ Alo, QKVArgs a)
{
    constexpr int N = Hc, K = Hc;
    __shared__ alignas(16) __bf16 AldsH[128 * 64];
    __shared__ alignas(16) __bf16 AldsL[128 * 64];
    __shared__ alignas(16) __bf16 BldsH[128 * 64];
    __shared__ alignas(16) __bf16 BldsL[128 * 64];

    const int tid  = threadIdx.x;
    const int lane = tid & 63;
    const int wave = tid >> 6;
    const int lr   = lane & 15;
    const int lg   = lane >> 4;
    const int gx   = blockIdx.x;
    const int widx = gx >> 3;
    const int n0   = (gx & 7) * 128;
    const int m0   = blockIdx.y * 128;
    const int wm   = (wave >> 1) * 64;
    const int wn   = (wave & 1) * 64;
    const int bn   = tid & 127;
    const int bkh  = (tid >> 7) * 32;

    const float* Bw   = (widx == 0) ? a.Wq : (widx == 1) ? a.Wk : a.Wv;
    const float* bias = (widx == 0) ? a.bq : (widx == 1) ? a.bk : a.bv;

    f32x4 acc[4][4] = {};
    const float* bsrc0 = Bw + (size_t)bkh * N + n0 + bn;

    for (int k0 = 0; k0 < K; k0 += 64) {
        #pragma unroll
        for (int c = 0; c < 4; ++c) {
            int li  = c * 256 + tid;
            int row = li >> 3;
            int lcb = ((li & 7) << 4) ^ ((row & 7) << 4);
            size_t goff = (size_t)(m0 + row) * K + k0 + (lcb >> 1);
            size_t loff = (size_t)(c * 256 + wave * 64) * 16;
            gload_lds16(Ahi + goff, (char*)AldsH + loff);
            gload_lds16(Alo + goff, (char*)AldsL + loff);
        }
        const float* bs = bsrc0 + (size_t)k0 * N;
        #pragma unroll
        for (int c = 0; c < 4; ++c) {
            bf16x8 ph, plv;
            #pragma unroll
            for (int j = 0; j < 8; ++j) {
                HL e = split2(bs[(size_t)(c * 8 + j) * N]);
                ph[j] = e.h;
                plv[j] = e.l;
            }
            int pcb = (bkh * 2 + c * 16) ^ ((bn & 7) << 4);
            *(bf16x8*)((char*)BldsH + bn * 128 + pcb) = ph;
            *(bf16x8*)((char*)BldsL + bn * 128 + pcb) = plv;
        }
        __syncthreads();

        bf16x8 ah[2][4], al[2][4], bh[2][4], bl[2][4];
        #pragma unroll
        for (int ks = 0; ks < 2; ++ks) {
            #pragma unroll
            for (int i = 0; i < 4; ++i) {
                int ra = wm + i * 16 + lr;
                int pa = (ks * 64 + lg * 16) ^ ((ra & 7) << 4);
                ah[ks][i] = *(const bf16x8*)((const char*)AldsH + ra * 128 + pa);
                al[ks][i] = *(const bf16x8*)((const char*)AldsL + ra * 128 + pa);
                int rb = wn + i * 16 + lr;
                int pb = (ks * 64 + lg * 16) ^ ((rb & 7) << 4);
                bh[ks][i] = *(const bf16x8*)((const char*)BldsH + rb * 128 + pb);
                bl[ks][i] = *(const bf16x8*)((const char*)BldsL + rb * 128 + pb);
            }
        }
        #pragma unroll
        for (int ks = 0; ks < 2; ++ks)
            #pragma unroll
            for (int mi = 0; mi < 4; ++mi)
                #pragma unroll
                for (int ni = 0; ni < 4; ++ni) {
                    acc[mi][ni] = mfma16(ah[ks][mi], bh[ks][ni], acc[mi][ni]);
                    acc[mi][ni] = mfma16(al[ks][mi], bh[ks][ni], acc[mi][ni]);
                    acc[mi][ni] = mfma16(ah[ks][mi], bl[ks][ni], acc[mi][ni]);
                }
        __syncthreads();
    }

    __bf16* outh = (widx == 0) ? a.qh : (widx == 1) ? a.kh : a.vv;
    __bf16* outl = (widx == 0) ? a.ql : a.kl;
    const float osc = (widx == 0) ? QSC : 1.f;
    #pragma unroll
    for (int ni = 0; ni < 4; ++ni) {
        int col = n0 + wn + ni * 16 + lr;
        float bv = bias[col];
        int hh = col >> 6, d = col & 63;
        #pragma unroll
        for (int mi = 0; mi < 4; ++mi) {
            int rowb = m0 + wm + mi * 16 + lg * 4;
            #pragma unroll
            for (int r = 0; r < 4; ++r) {
                int row = rowb + r;
                int bb = row >> 11, s = row & (Sc - 1);
                size_t idx = ((size_t)(bb * NHc + hh) * Sc + s) * HDc + d;
                float v = (acc[mi][ni][r] + bv) * osc;
                if (widx < 2) {
                    HL e = split2(v);
                    outh[idx] = e.h;
                    outl[idx] = e.l;
                } else {
                    outh[idx] = (__bf16)v;
                }
            }
        }
    }
}

// ---------------------------------------------------------------------------
// Flash attention v3 (unchanged this round). Scores in log2 units.
// ---------------------------------------------------------------------------
template<int QKSPLIT>
__global__ __launch_bounds__(256) void attn_kernel(
    const __bf16* __restrict__ Qh, const __bf16* __restrict__ Ql,
    const __bf16* __restrict__ Kh, const __bf16* __restrict__ Kl,
    const __bf16* __restrict__ V, __bf16* __restrict__ O)
{
    __shared__ alignas(16) __bf16 Ksh[2][64 * 64];
    __shared__ alignas(16) __bf16 Klo[QKSPLIT ? 2 : 1][QKSPLIT ? 64 * 64 : 8];
    __shared__ alignas(16) __bf16 VT[2][64 * 64];

    const int tid = threadIdx.x;
    const int lane = tid & 63, wave = tid >> 6;
    const int lr = lane & 15, lg = lane >> 4;
    const int h = blockIdx.y, b = blockIdx.z;
    const int q0 = blockIdx.x * 64 + wave * 16;

    const size_t headoff = ((size_t)b * NHc + h) * Sc * HDc;
    const __bf16* Qb  = Qh + headoff;
    const __bf16* Kb  = Kh + headoff;
    const __bf16* Klb = QKSPLIT ? (Kl + headoff) : nullptr;
    const __bf16* Vb  = V + headoff;

    const size_t qrow = (size_t)(q0 + lr) * HDc;
    bf16x8 qf0 = *(const bf16x8*)(Qb + qrow + lg * 8);
    bf16x8 qf1 = *(const bf16x8*)(Qb + qrow + 32 + lg * 8);
    bf16x8 qlo0, qlo1;
    if constexpr (QKSPLIT) {
        const __bf16* Qlb = Ql + headoff;
        qlo0 = *(const bf16x8*)(Qlb + qrow + lg * 8);
        qlo1 = *(const bf16x8*)(Qlb + qrow + 32 + lg * 8);
    }

    const int kp = tid & 31, dblk = tid >> 5;
    const int sp = (kp & 0x11) | ((kp & 0x06) << 1) | ((kp & 0x08) >> 2);

    auto stageK = [&](int kt, int buf) {
        #pragma unroll
        for (int c = 0; c < 2; ++c) {
            int li  = c * 256 + tid;
            int row = li >> 3;
            int lcb = ((li & 7) << 4) ^ ((row & 7) << 4);
            size_t goff = (size_t)(kt * 64 + row) * HDc + (lcb >> 1);
            size_t loff = (size_t)(c * 256 + wave * 64) * 16;
            gload_lds16(Kb + goff, (char*)Ksh[buf] + loff);
            if constexpr (QKSPLIT)
                gload_lds16(Klb + goff, (char*)Klo[buf] + loff);
        }
    };
    auto loadV = [&](int kt, bf16x8& va, bf16x8& vb2) {
        const __bf16* vs = Vb + (size_t)(kt * 64 + 2 * kp) * HDc + dblk * 8;
        va  = *(const bf16x8*)vs;
        vb2 = *(const bf16x8*)(vs + HDc);
    };
    auto writeVT = [&](int buf, bf16x8 va, bf16x8 vb2) {
        #pragma unroll
        for (int j = 0; j < 8; ++j) {
            int d = dblk * 8 + j;
            unsigned u = bfbits(va[j]) | (bfbits(vb2[j]) << 16);
            int byte = d * 128 + ((sp * 4) ^ ((d & 7) << 4));
            *(unsigned*)((char*)VT[buf] + byte) = u;
        }
    };

    f32x4 o[4] = {};
    float m = -1e30f, lsum = 0.f;

    stageK(0, 0);
    {
        bf16x8 va, vb2;
        loadV(0, va, vb2);
        writeVT(0, va, vb2);
    }
    __syncthreads();

    int cur = 0;
    for (int kt = 0; kt < Sc / 64; ++kt) {
        const int nb = cur ^ 1;
        const bool pf = (kt + 1 < Sc / 64);
        bf16x8 va, vb2;
        if (pf) {
            stageK(kt + 1, nb);
            loadV(kt + 1, va, vb2);
        }

        const char* Kc = (const char*)Ksh[cur];
        const char* Klc = (const char*)Klo[QKSPLIT ? cur : 0];
        f32x4 s[4];
        #pragma unroll
        for (int kg = 0; kg < 4; ++kg) {
            int ra = kg * 16 + lr;
            int pa0 = (lg * 16) ^ ((ra & 7) << 4);
            int pa1 = (64 + lg * 16) ^ ((ra & 7) << 4);
            bf16x8 kf0 = *(const bf16x8*)(Kc + ra * 128 + pa0);
            bf16x8 kf1 = *(const bf16x8*)(Kc + ra * 128 + pa1);
            f32x4 t = {};
            t = mfma16(kf0, qf0, t);
            t = mfma16(kf1, qf1, t);
            if constexpr (QKSPLIT) {
                bf16x8 kg0 = *(const bf16x8*)(Klc + ra * 128 + pa0);
                bf16x8 kg1 = *(const bf16x8*)(Klc + ra * 128 + pa1);
                t = mfma16(kg0, qf0, t);
                t = mfma16(kg1, qf1, t);
                t = mfma16(kf0, qlo0, t);
                t = mfma16(kf1, qlo1, t);
            }
            s[kg] = t;
        }

        float mt = -1e30f;
        #pragma unroll
        for (int kg = 0; kg < 4; ++kg)
            #pragma unroll
            for (int r = 0; r < 4; ++r)
                mt = fmaxf(mt, s[kg][r]);
        mt = fmaxf(mt, __shfl_xor(mt, 16));
        mt = fmaxf(mt, __shfl_xor(mt, 32));
        if (!__all(mt <= m + 8.f)) {
            float mnew = fmaxf(m, mt);
            float fac = EXP2(m - mnew);
            m = mnew;
            lsum *= fac;
            #pragma unroll
            for (int r = 0; r < 4; ++r) {
                float fr = __shfl(fac, (lg << 4) | (lg * 4 + r));
                #pragma unroll
                for (int nd = 0; nd < 4; ++nd) o[nd][r] *= fr;
            }
        }
        float ps = 0.f;
        #pragma unroll
        for (int kg = 0; kg < 4; ++kg)
            #pragma unroll
            for (int r = 0; r < 4; ++r) {
                float p = EXP2(s[kg][r] - m);
                ps += p;
                s[kg][r] = p;
            }
        ps += __shfl_xor(ps, 16);
        ps += __shfl_xor(ps, 32);
        lsum += ps;

        #pragma unroll
        for (int kh2 = 0; kh2 < 2; ++kh2) {
            u32x4 pk;
            pk[0] = packbf(s[2 * kh2][0],     s[2 * kh2][1]);
            pk[1] = packbf(s[2 * kh2][2],     s[2 * kh2][3]);
            pk[2] = packbf(s[2 * kh2 + 1][0], s[2 * kh2 + 1][1]);
            pk[3] = packbf(s[2 * kh2 + 1][2], s[2 * kh2 + 1][3]);
            bf16x8 paf = __builtin_bit_cast(bf16x8, pk);
            #pragma unroll
            for (int nd = 0; nd < 4; ++nd) {
                int d = nd * 16 + lr;
                int byte = d * 128 + ((64 * kh2 + 16 * lg) ^ ((d & 7) << 4));
                bf16x8 vbf = *(const bf16x8*)((const char*)VT[cur] + byte);
                o[nd] = mfma16(paf, vbf, o[nd]);
            }
        }

        if (pf) writeVT(nb, va, vb2);
        __syncthreads();
        cur = nb;
    }

    #pragma unroll
    for (int r = 0; r < 4; ++r) {
        float lv  = __shfl(lsum, (lg << 4) | (lg * 4 + r));
        float inv = 1.f / lv;
        size_t orow = ((size_t)b * Sc + q0 + lg * 4 + r) * Hc + h * HDc;
        #pragma unroll
        for (int nd = 0; nd < 4; ++nd)
            O[orow + nd * 16 + lr] = (__bf16)(o[nd][r] * inv);
    }
}

// ---------------------------------------------------------------------------
// Fused residual + LayerNorm: y bf16. f32 master + bf16 copy out.
// ---------------------------------------------------------------------------
__global__ __launch_bounds__(256) void ln_kernel(
    const float* __restrict__ xr, const __bf16* __restrict__ y,
    const float* __restrict__ g, const float* __restrict__ beta,
    float* __restrict__ of, __bf16* __restrict__ oh)
{
    __shared__ float red[2][4];
    const int row = blockIdx.x, t = threadIdx.x;
    const int lane = t & 63, wave = t >> 6;
    const int idx = row * 256 + t;
    float4 a = ((const float4*)xr)[idx];
    bf16x4 cb = ((const bf16x4*)y)[idx];
    float4 v;
    v.x = a.x + (float)cb[0]; v.y = a.y + (float)cb[1];
    v.z = a.z + (float)cb[2]; v.w = a.w + (float)cb[3];
    float s1 = v.x + v.y + v.z + v.w;
    float s2 = v.x * v.x + v.y * v.y + v.z * v.z + v.w * v.w;
    #pragma unroll
    for (int off = 1; off < 64; off <<= 1) {
        s1 += __shfl_xor(s1, off);
        s2 += __shfl_xor(s2, off);
    }
    if (lane == 0) { red[0][wave] = s1; red[1][wave] = s2; }
    __syncthreads();
    s1 = red[0][0] + red[0][1] + red[0][2] + red[0][3];
    s2 = red[1][0] + red[1][1] + red[1][2] + red[1][3];
    const float mu   = s1 * (1.f / Hc);
    const float var  = s2 * (1.f / Hc) - mu * mu;
    const float rstd = rsqrtf(var + EPSc);
    float4 gg = ((const float4*)g)[t];
    float4 bb = ((const float4*)beta)[t];
    float4 r;
    r.x = (v.x - mu) * rstd * gg.x + bb.x;
    r.y = (v.y - mu) * rstd * gg.y + bb.y;
    r.z = (v.z - mu) * rstd * gg.z + bb.z;
    r.w = (v.w - mu) * rstd * gg.w + bb.w;
    ((float4*)of)[idx] = r;
    bf16x4 hh = { (__bf16)r.x, (__bf16)r.y, (__bf16)r.z, (__bf16)r.w };
    ((bf16x4*)oh)[idx] = hh;
}

// ---------------------------------------------------------------------------
extern "C" void kernel_launch(void* const* d_in, const int* in_sizes, int n_in,
                              void* d_out, int out_size, void* d_ws, size_t ws_size,
                              hipStream_t stream)
{
    const float* inp = (const float*)d_in[0];
    const float* pos = (const float*)d_in[1];
    const float* Wq  = (const float*)d_in[2];
    const float* bq  = (const float*)d_in[3];
    const float* Wk  = (const float*)d_in[4];
    const float* bk  = (const float*)d_in[5];
    const float* Wv  = (const float*)d_in[6];
    const float* bv  = (const float*)d_in[7];
    const float* Wo  = (const float*)d_in[8];
    const float* bo  = (const float*)d_in[9];
    const float* lng = (const float*)d_in[10];
    const float* lnb = (const float*)d_in[11];
    const float* W1  = (const float*)d_in[12];
    const float* b1  = (const float*)d_in[13];
    const float* W2  = (const float*)d_in[14];
    const float* b2  = (const float*)d_in[15];

    char* ws = (char*)d_ws;
    const size_t MB = 1u << 20;
    float*  src_f = (float*)(ws);              // 16 MB
    __bf16* src_h = (__bf16*)(ws + 16 * MB);   //  8 MB
    __bf16* src_l = (__bf16*)(ws + 24 * MB);   //  8 MB
    __bf16* qh    = (__bf16*)(ws + 32 * MB);   //  8 MB (head-major)
    __bf16* kh    = (__bf16*)(ws + 40 * MB);   //  8 MB
    __bf16* vv    = (__bf16*)(ws + 48 * MB);   //  8 MB
    __bf16* ctx   = (__bf16*)(ws + 56 * MB);   //  8 MB (row-major)
    __bf16* ql    = (__bf16*)(ws + 64 * MB);   //  8 MB (layer 0 only)
    __bf16* kl    = (__bf16*)(ws + 72 * MB);   //  8 MB
    __bf16* tmpb  = (__bf16*)(ws + 80 * MB);   //  8 MB (bf16 GEMM out)
    __bf16* h1    = (__bf16*)(ws + 32 * MB);   // 32 MB alias (qh..ctx, dead by FFN)
    __bf16* wqT   = (__bf16*)(ws + 96 * MB);   // 12 MB each
    __bf16* wkT   = (__bf16*)(ws + 108 * MB);
    __bf16* wvT   = (__bf16*)(ws + 120 * MB);
    __bf16* woT   = (__bf16*)(ws + 132 * MB);
    __bf16* w1T   = (__bf16*)(ws + 144 * MB);  // 48 MB
    __bf16* w2T   = (__bf16*)(ws + 192 * MB);  // 48 MB ; total 240 MB

    const int M = Bc * Sc;  // 4096

    wconv_kernel<<<dim3(16, 16, 6), 256, 0, stream>>>(Wq, wqT, Hc, Hc);
    wconv_kernel<<<dim3(16, 16, 6), 256, 0, stream>>>(Wk, wkT, Hc, Hc);
    wconv_kernel<<<dim3(16, 16, 6), 256, 0, stream>>>(Wv, wvT, Hc, Hc);
    wconv_kernel<<<dim3(16, 16, 6), 256, 0, stream>>>(Wo, woT, Hc, Hc);
    wconv_kernel<<<dim3(64, 16, 6), 256, 0, stream>>>(W1, w1T, Hc, PFc);
    wconv_kernel<<<dim3(16, 64, 6), 256, 0, stream>>>(W2, w2T, PFc, Hc);

    embed_kernel<<<2048, 256, 0, stream>>>(inp, pos, src_f, src_h, src_l);

    for (int l = 0; l < Lc; ++l) {
        const size_t wHH = (size_t)l * Hc * Hc;
        const size_t wH  = (size_t)l * Hc;
        if (l == 0) {
            QKVArgs qa = { Wq, Wk, Wv, bq, bk, bv, qh, ql, kh, kl, vv };
            qkv0_kernel<<<dim3(24, 32), 256, 0, stream>>>(src_h, src_l, qa);
            attn_kernel<1><<<dim3(32, 16, 2), 256, 0, stream>>>(qh, ql, kh, kl, vv, ctx);
        } else {
            QKVBT qa = { wqT + wHH, wkT + wHH, wvT + wHH, bq + wH, bk + wH, bv + wH,
                         qh, kh, vv };
            qkv_bt_kernel<<<dim3(24, 32), 256, 0, stream>>>(src_h, qa);
            attn_kernel<0><<<dim3(32, 16, 2), 256, 0, stream>>>(qh, nullptr, kh, nullptr, vv, ctx);
        }
        gemm_bt_kernel<64, 1, false><<<dim3(8, 64), 256, 0, stream>>>(
            ctx, woT + wHH, bo + wH, tmpb, M, Hc, Hc);
        ln_kernel<<<M, 256, 0, stream>>>(src_f, tmpb, lng + wH, lnb + wH, src_f, src_h);
        gemm_bt_kernel<128, 1, true><<<dim3(32, 32), 256, 0, stream>>>(
            src_h, w1T + (size_t)l * Hc * PFc, b1 + (size_t)l * PFc, h1, M, PFc, Hc);
        gemm_bt_kernel<64, 1, false><<<dim3(8, 64), 256, 0, stream>>>(
            h1, w2T + (size_t)l * PFc * Hc, b2 + wH, tmpb, M, Hc, PFc);
        float* dst = (l == Lc - 1) ? (float*)d_out : src_f;
        ln_kernel<<<M, 256, 0, stream>>>(src_f, tmpb, lng + wH, lnb + wH, dst, src_h);
    }
}